// Round 2
// baseline (1193.212 us; speedup 1.0000x reference)
//
#include <hip/hip_runtime.h>
#include <math.h>

#define N_NODES   100000
#define N_EDGES   1600000
#define N_GRAPHS  512
#define FEAT      128
#define EXTRA     8

#define SCHUNK 512
#define SNBLK ((N_NODES + SCHUNK - 1) / SCHUNK)   // 196

static __device__ __forceinline__ float selu_f(float x){
    const float alpha = 1.6732632423543772f;
    const float scale = 1.0507009873554805f;
    return scale * (x > 0.0f ? x : alpha * expm1f(x));
}

__global__ void k_zero_i4(int4* __restrict__ p, int n4){
    int i = blockIdx.x*blockDim.x + threadIdx.x;
    if (i < n4) p[i] = make_int4(0,0,0,0);
}

__global__ void k_count(const int* __restrict__ esrc, const int* __restrict__ edst,
                        int* __restrict__ cs, int* __restrict__ cd){
    int e = blockIdx.x*blockDim.x + threadIdx.x;
    if (e < N_EDGES){
        atomicAdd(&cs[esrc[e]], 1);
        atomicAdd(&cd[edst[e]], 1);
    }
}

__global__ void k_norms(const int* __restrict__ cs, const int* __restrict__ cd,
                        float* __restrict__ ns, float* __restrict__ nd){
    int i = blockIdx.x*blockDim.x + threadIdx.x;
    if (i < N_NODES){
        ns[i] = rsqrtf((float)(cs[i] > 1 ? cs[i] : 1));
        nd[i] = rsqrtf((float)(cd[i] > 1 ? cd[i] : 1));
    }
}

__global__ void k_scan1(const int* __restrict__ cnt, int* __restrict__ bsum){
    __shared__ int red[256];
    int b = blockIdx.x, t = threadIdx.x;
    int i0 = b*SCHUNK + t;
    int i1 = i0 + 256;
    int v = 0;
    if (i0 < N_NODES) v += cnt[i0];
    if (i1 < N_NODES) v += cnt[i1];
    red[t] = v; __syncthreads();
    for (int s = 128; s > 0; s >>= 1){
        if (t < s) red[t] += red[t+s];
        __syncthreads();
    }
    if (t == 0) bsum[b] = red[0];
}

__global__ void k_scan2(const int* __restrict__ bsum, int* __restrict__ boff,
                        int* __restrict__ row_ptr_tail){
    if (threadIdx.x == 0 && blockIdx.x == 0){
        int run = 0;
        for (int i = 0; i < SNBLK; ++i){ boff[i] = run; run += bsum[i]; }
        if (row_ptr_tail) row_ptr_tail[N_NODES] = N_EDGES;
    }
}

__global__ void k_scan3(const int* __restrict__ cnt, const int* __restrict__ boff,
                        int* __restrict__ row_ptr, int* __restrict__ cursor){
    __shared__ int sc[256];
    int b = blockIdx.x, t = threadIdx.x;
    int base = b*SCHUNK;
    int e0 = base + 2*t, e1 = e0 + 1;
    int a0 = (e0 < N_NODES) ? cnt[e0] : 0;
    int a1 = (e1 < N_NODES) ? cnt[e1] : 0;
    int s = a0 + a1;
    sc[t] = s; __syncthreads();
    for (int d = 1; d < 256; d <<= 1){
        int v = (t >= d) ? sc[t-d] : 0;
        __syncthreads();
        sc[t] += v;
        __syncthreads();
    }
    int excl = sc[t] - s + boff[b];
    if (e0 < N_NODES){ if (row_ptr) row_ptr[e0] = excl;      cursor[e0] = excl; }
    if (e1 < N_NODES){ if (row_ptr) row_ptr[e1] = excl + a0; cursor[e1] = excl + a0; }
}

// scatter edges into src-grouped (CSC) order
__global__ void k_scatter_src(const int* __restrict__ esrc, const int* __restrict__ edst,
                              int* __restrict__ scursor,
                              int* __restrict__ csc_src, int* __restrict__ csc_dst){
    int e = blockIdx.x*blockDim.x + threadIdx.x;
    if (e < N_EDGES){
        int s = esrc[e];
        int p = atomicAdd(&scursor[s], 1);
        csc_src[p] = s;
        csc_dst[p] = edst[e];
    }
}

// scatter CSC-ordered edges into dst lists: grid order ~ ascending src,
// so each dst list ends up approximately sorted by src (L2 locality in gather)
__global__ void k_scatter_dst(const int* __restrict__ csc_src, const int* __restrict__ csc_dst,
                              int* __restrict__ cursor, int* __restrict__ col){
    int p = blockIdx.x*blockDim.x + threadIdx.x;
    if (p < N_EDGES){
        int d = csc_dst[p];
        int q = atomicAdd(&cursor[d], 1);
        col[q] = csc_src[p];
    }
}

// one wave (64 lanes) per node, 2 feats per lane
__global__ __launch_bounds__(256) void k_aggregate(
        const float* __restrict__ x, const int* __restrict__ row_ptr,
        const int* __restrict__ col, const float* __restrict__ ns,
        const float* __restrict__ nd, float* __restrict__ out){
    int gid  = blockIdx.x*blockDim.x + threadIdx.x;
    int node = gid >> 6;
    int lane = gid & 63;
    if (node >= N_NODES) return;
    int beg = row_ptr[node], end = row_ptr[node+1];
    const float2* __restrict__ x2 = (const float2*)x;
    float ax = 0.f, ay = 0.f;
    for (int e = beg; e < end; ++e){
        int s = col[e];
        float w = ns[s];
        float2 v = x2[(size_t)s*64 + lane];
        ax = fmaf(w, v.x, ax);
        ay = fmaf(w, v.y, ay);
    }
    float wd = nd[node];
    ((float2*)out)[(size_t)node*64 + lane] = make_float2(ax*wd, ay*wd);
}

// in-place row GEMM: x[32 rows] = act(x @ W + b); W staged in two 32KB halves
template<int ACT>
__global__ __launch_bounds__(256) void k_gemm(float* __restrict__ xb,
        const float* __restrict__ W, const float* __restrict__ bias){
    __shared__ float Wl[64*FEAT];   // 32 KB
    __shared__ float Xl[32*FEAT];   // 16 KB
    int t = threadIdx.x;
    size_t row0 = (size_t)blockIdx.x * 32;
    {
        const float4* src = (const float4*)(xb + row0*FEAT);
        float4* dst = (float4*)Xl;
        for (int i = t; i < 32*FEAT/4; i += 256) dst[i] = src[i];
    }
    int cb = (t & 31) * 4;
    int rb = (t >> 5) * 4;
    float acc[4][4] = {};
    for (int half = 0; half < 2; ++half){
        __syncthreads();
        {
            const float4* src = (const float4*)(W + half*64*FEAT);
            float4* dst = (float4*)Wl;
            for (int i = t; i < 64*FEAT/4; i += 256) dst[i] = src[i];
        }
        __syncthreads();
        for (int k = 0; k < 64; k += 4){
            float a[4][4], w[4][4];
            for (int r = 0; r < 4; ++r){
                float4 v = *(const float4*)&Xl[(rb+r)*FEAT + half*64 + k];
                a[r][0]=v.x; a[r][1]=v.y; a[r][2]=v.z; a[r][3]=v.w;
            }
            for (int kk = 0; kk < 4; ++kk){
                float4 v = *(const float4*)&Wl[(k+kk)*FEAT + cb];
                w[kk][0]=v.x; w[kk][1]=v.y; w[kk][2]=v.z; w[kk][3]=v.w;
            }
            for (int r = 0; r < 4; ++r)
                for (int c = 0; c < 4; ++c)
                    acc[r][c] += a[r][0]*w[0][c] + a[r][1]*w[1][c]
                               + a[r][2]*w[2][c] + a[r][3]*w[3][c];
        }
    }
    float4 bv = *(const float4*)&bias[cb];
    for (int r = 0; r < 4; ++r){
        float4 o;
        o.x = acc[r][0]+bv.x; o.y = acc[r][1]+bv.y;
        o.z = acc[r][2]+bv.z; o.w = acc[r][3]+bv.w;
        if (ACT){ o.x=selu_f(o.x); o.y=selu_f(o.y); o.z=selu_f(o.z); o.w=selu_f(o.w); }
        *(float4*)&xb[(row0 + rb + r)*FEAT + cb] = o;
    }
}

__global__ void k_goff(const int* __restrict__ gid, int* __restrict__ goff){
    int g = blockIdx.x*blockDim.x + threadIdx.x;
    if (g > N_GRAPHS) return;
    if (g == N_GRAPHS){ goff[g] = N_NODES; return; }
    int lo = 0, hi = N_NODES;
    while (lo < hi){
        int mid = (lo + hi) >> 1;
        if (gid[mid] < g) lo = mid + 1; else hi = mid;
    }
    goff[g] = lo;
}

// block per graph, 128 threads = feature columns; segment mean
__global__ void k_readout(const float* __restrict__ x, const int* __restrict__ goff,
                          float* __restrict__ emb){
    int g = blockIdx.x, f = threadIdx.x;
    int beg = goff[g], end = goff[g+1];
    float s = 0.f;
    for (int n = beg; n < end; ++n) s += x[(size_t)n*FEAT + f];
    int c = end - beg; if (c < 1) c = 1;
    emb[g*FEAT + f] = s / (float)c;
}

// block per graph: 136 -> 256 -> 128 -> 1 fused MLP head
__global__ __launch_bounds__(256) void k_mlp(
        const float* __restrict__ emb, const float* __restrict__ fg,
        const float* __restrict__ Wl1, const float* __restrict__ bl1,
        const float* __restrict__ Wl2, const float* __restrict__ bl2,
        const float* __restrict__ Wl3, const float* __restrict__ bl3,
        float* __restrict__ out){
    __shared__ float in136[FEAT+EXTRA];
    __shared__ float y1[256];
    __shared__ float y2[128];
    int g = blockIdx.x, t = threadIdx.x;
    if (t < FEAT)            in136[t] = emb[g*FEAT + t];
    else if (t < FEAT+EXTRA) in136[t] = fg[g*EXTRA + (t-FEAT)];
    __syncthreads();
    {
        float acc = bl1[t];
        for (int i = 0; i < FEAT+EXTRA; ++i) acc += in136[i] * Wl1[i*256 + t];
        y1[t] = selu_f(acc);
    }
    __syncthreads();
    if (t < 128){
        float acc = bl2[t];
        for (int i = 0; i < 256; ++i) acc += y1[i] * Wl2[i*128 + t];
        y2[t] = selu_f(acc);
    }
    __syncthreads();
    if (t == 0){
        float s = bl3[0];
        for (int i = 0; i < 128; ++i) s += y2[i] * Wl3[i];
        out[g] = s;
    }
}

extern "C" void kernel_launch(void* const* d_in, const int* in_sizes, int n_in,
                              void* d_out, int out_size, void* d_ws, size_t ws_size,
                              hipStream_t stream){
    const float* feats_node  = (const float*)d_in[0];
    const float* feats_graph = (const float*)d_in[1];
    const int*   edge_src    = (const int*)d_in[2];
    const int*   edge_dst    = (const int*)d_in[3];
    const int*   graph_ids   = (const int*)d_in[4];
    const float* W1 =(const float*)d_in[5];  const float* b1 =(const float*)d_in[6];
    const float* W2 =(const float*)d_in[7];  const float* b2 =(const float*)d_in[8];
    const float* W3 =(const float*)d_in[9];  const float* b3 =(const float*)d_in[10];
    const float* Wl1=(const float*)d_in[11]; const float* bl1=(const float*)d_in[12];
    const float* Wl2=(const float*)d_in[13]; const float* bl2=(const float*)d_in[14];
    const float* Wl3=(const float*)d_in[15]; const float* bl3=(const float*)d_in[16];
    float* out = (float*)d_out;
    (void)in_sizes; (void)n_in; (void)out_size; (void)ws_size;

    // workspace layout (~112 MB total)
    char* ws = (char*)d_ws;
    size_t off = 0;
    auto alloc = [&](size_t bytes)->void*{
        void* p = ws + off;
        off += (bytes + 255) & ~(size_t)255;
        return p;
    };
    float* bufA    = (float*)alloc((size_t)N_NODES*FEAT*4);
    float* bufB    = (float*)alloc((size_t)N_NODES*FEAT*4);
    float* ns      = (float*)alloc((size_t)N_NODES*4);
    float* nd      = (float*)alloc((size_t)N_NODES*4);
    int*   cnt     = (int*)  alloc((size_t)2*N_NODES*4);
    int*   cnt_src = cnt;
    int*   cnt_dst = cnt + N_NODES;
    int*   row_ptr = (int*)  alloc((size_t)(N_NODES+1)*4);
    int*   cursor  = (int*)  alloc((size_t)N_NODES*4);
    int*   col     = (int*)  alloc((size_t)N_EDGES*4);
    int*   bsum    = (int*)  alloc((size_t)SNBLK*4);
    int*   boff    = (int*)  alloc((size_t)SNBLK*4);
    int*   bsum2   = (int*)  alloc((size_t)SNBLK*4);
    int*   boff2   = (int*)  alloc((size_t)SNBLK*4);
    int*   goff    = (int*)  alloc((size_t)(N_GRAPHS+1)*4);
    float* emb     = (float*)alloc((size_t)N_GRAPHS*FEAT*4);

    // CSC temporaries aliased into bufB (bufB first written by 2nd aggregate,
    // after the CSR build is complete). bufB = 51.2 MB >= 13.2 MB needed.
    int* scursor = (int*)bufB;                       // N_NODES
    int* csc_src = (int*)(bufB + N_NODES);           // N_EDGES
    int* csc_dst = (int*)(bufB + N_NODES + N_EDGES); // N_EDGES

    // degree counting + norms
    k_zero_i4<<<dim3((2*N_NODES/4 + 255)/256), dim3(256), 0, stream>>>((int4*)cnt, 2*N_NODES/4);
    k_count<<<dim3((N_EDGES+255)/256), dim3(256), 0, stream>>>(edge_src, edge_dst, cnt_src, cnt_dst);
    k_norms<<<dim3((N_NODES+255)/256), dim3(256), 0, stream>>>(cnt_src, cnt_dst, ns, nd);

    // CSR build (by dst), with dst lists approximately sorted by src:
    // 1) scan dst counts -> row_ptr + cursor
    k_scan1<<<dim3(SNBLK), dim3(256), 0, stream>>>(cnt_dst, bsum);
    k_scan2<<<dim3(1), dim3(64), 0, stream>>>(bsum, boff, row_ptr);
    k_scan3<<<dim3(SNBLK), dim3(256), 0, stream>>>(cnt_dst, boff, row_ptr, cursor);
    // 2) scan src counts -> scursor (CSC cursors)
    k_scan1<<<dim3(SNBLK), dim3(256), 0, stream>>>(cnt_src, bsum2);
    k_scan2<<<dim3(1), dim3(64), 0, stream>>>(bsum2, boff2, (int*)nullptr);
    k_scan3<<<dim3(SNBLK), dim3(256), 0, stream>>>(cnt_src, boff2, (int*)nullptr, scursor);
    // 3) edges -> CSC order (grouped by src)
    k_scatter_src<<<dim3((N_EDGES+255)/256), dim3(256), 0, stream>>>(
        edge_src, edge_dst, scursor, csc_src, csc_dst);
    // 4) CSC order -> dst lists (approx ascending src within each list)
    k_scatter_dst<<<dim3((N_EDGES+255)/256), dim3(256), 0, stream>>>(
        csc_src, csc_dst, cursor, col);

    // 3 GraphConv layers (aggregate then in-place GEMM+bias(+SELU))
    dim3 aggGrid((N_NODES*64 + 255)/256);
    k_aggregate<<<aggGrid, dim3(256), 0, stream>>>(feats_node, row_ptr, col, ns, nd, bufA);
    k_gemm<1><<<dim3(N_NODES/32), dim3(256), 0, stream>>>(bufA, W1, b1);
    k_aggregate<<<aggGrid, dim3(256), 0, stream>>>(bufA, row_ptr, col, ns, nd, bufB);
    k_gemm<1><<<dim3(N_NODES/32), dim3(256), 0, stream>>>(bufB, W2, b2);
    k_aggregate<<<aggGrid, dim3(256), 0, stream>>>(bufB, row_ptr, col, ns, nd, bufA);
    k_gemm<0><<<dim3(N_NODES/32), dim3(256), 0, stream>>>(bufA, W3, b3);

    // readout + MLP head
    k_goff<<<dim3((N_GRAPHS+1+255)/256), dim3(256), 0, stream>>>(graph_ids, goff);
    k_readout<<<dim3(N_GRAPHS), dim3(FEAT), 0, stream>>>(bufA, goff, emb);
    k_mlp<<<dim3(N_GRAPHS), dim3(256), 0, stream>>>(emb, feats_graph,
        Wl1, bl1, Wl2, bl2, Wl3, bl3, out);
}

// Round 3
// 1043.179 us; speedup vs baseline: 1.1438x; 1.1438x over previous
//
#include <hip/hip_runtime.h>
#include <hip/hip_fp16.h>
#include <math.h>

#define N_NODES   100000
#define N_EDGES   1600000
#define N_GRAPHS  512
#define FEAT      128
#define EXTRA     8

#define SCHUNK 512
#define SNBLK ((N_NODES + SCHUNK - 1) / SCHUNK)   // 196

static __device__ __forceinline__ float selu_f(float x){
    const float alpha = 1.6732632423543772f;
    const float scale = 1.0507009873554805f;
    return scale * (x > 0.0f ? x : alpha * expm1f(x));
}

__global__ void k_zero_i4(int4* __restrict__ p, int n4){
    int i = blockIdx.x*blockDim.x + threadIdx.x;
    if (i < n4) p[i] = make_int4(0,0,0,0);
}

__global__ void k_count(const int* __restrict__ esrc, const int* __restrict__ edst,
                        int* __restrict__ cs, int* __restrict__ cd){
    int e = blockIdx.x*blockDim.x + threadIdx.x;
    if (e < N_EDGES){
        atomicAdd(&cs[esrc[e]], 1);
        atomicAdd(&cd[edst[e]], 1);
    }
}

__global__ void k_norms(const int* __restrict__ cs, const int* __restrict__ cd,
                        float* __restrict__ ns, float* __restrict__ nd){
    int i = blockIdx.x*blockDim.x + threadIdx.x;
    if (i < N_NODES){
        ns[i] = rsqrtf((float)(cs[i] > 1 ? cs[i] : 1));
        nd[i] = rsqrtf((float)(cd[i] > 1 ? cd[i] : 1));
    }
}

__global__ void k_scan1(const int* __restrict__ cnt, int* __restrict__ bsum){
    __shared__ int red[256];
    int b = blockIdx.x, t = threadIdx.x;
    int i0 = b*SCHUNK + t;
    int i1 = i0 + 256;
    int v = 0;
    if (i0 < N_NODES) v += cnt[i0];
    if (i1 < N_NODES) v += cnt[i1];
    red[t] = v; __syncthreads();
    for (int s = 128; s > 0; s >>= 1){
        if (t < s) red[t] += red[t+s];
        __syncthreads();
    }
    if (t == 0) bsum[b] = red[0];
}

__global__ void k_scan2(const int* __restrict__ bsum, int* __restrict__ boff,
                        int* __restrict__ row_ptr_tail){
    if (threadIdx.x == 0 && blockIdx.x == 0){
        int run = 0;
        for (int i = 0; i < SNBLK; ++i){ boff[i] = run; run += bsum[i]; }
        if (row_ptr_tail) row_ptr_tail[N_NODES] = N_EDGES;
    }
}

__global__ void k_scan3(const int* __restrict__ cnt, const int* __restrict__ boff,
                        int* __restrict__ row_ptr, int* __restrict__ cursor){
    __shared__ int sc[256];
    int b = blockIdx.x, t = threadIdx.x;
    int base = b*SCHUNK;
    int e0 = base + 2*t, e1 = e0 + 1;
    int a0 = (e0 < N_NODES) ? cnt[e0] : 0;
    int a1 = (e1 < N_NODES) ? cnt[e1] : 0;
    int s = a0 + a1;
    sc[t] = s; __syncthreads();
    for (int d = 1; d < 256; d <<= 1){
        int v = (t >= d) ? sc[t-d] : 0;
        __syncthreads();
        sc[t] += v;
        __syncthreads();
    }
    int excl = sc[t] - s + boff[b];
    if (e0 < N_NODES){ row_ptr[e0] = excl;      cursor[e0] = excl; }
    if (e1 < N_NODES){ row_ptr[e1] = excl + a0; cursor[e1] = excl + a0; }
}

__global__ void k_scatter(const int* __restrict__ esrc, const int* __restrict__ edst,
                          int* __restrict__ cursor, int* __restrict__ col){
    int e = blockIdx.x*blockDim.x + threadIdx.x;
    if (e < N_EDGES){
        int d = edst[e];
        int p = atomicAdd(&cursor[d], 1);
        col[p] = esrc[e];
    }
}

// xh[i] = fp16( x[i] * ns[node] )  -- norm_src pre-folded
__global__ void k_prep(const float2* __restrict__ x2, const float* __restrict__ ns,
                       __half2* __restrict__ xh2){
    int i = blockIdx.x*blockDim.x + threadIdx.x;
    if (i < N_NODES*64){
        int node = i >> 6;
        float w = ns[node];
        float2 v = x2[i];
        xh2[i] = __floats2half2_rn(v.x*w, v.y*w);
    }
}

// one wave (64 lanes) per node, 2 feats per lane; input fp16 pre-scaled by ns
__global__ __launch_bounds__(256) void k_aggregate_h(
        const __half2* __restrict__ xh, const int* __restrict__ row_ptr,
        const int* __restrict__ col, const float* __restrict__ nd,
        float* __restrict__ out){
    int gid  = blockIdx.x*blockDim.x + threadIdx.x;
    int node = gid >> 6;
    int lane = gid & 63;
    if (node >= N_NODES) return;
    int beg = row_ptr[node], end = row_ptr[node+1];
    float ax = 0.f, ay = 0.f;
    for (int e = beg; e < end; ++e){
        int s = col[e];
        float2 v = __half22float2(xh[(size_t)s*64 + lane]);
        ax += v.x;
        ay += v.y;
    }
    float wd = nd[node];
    ((float2*)out)[(size_t)node*64 + lane] = make_float2(ax*wd, ay*wd);
}

// row GEMM: out = act(xin @ W + b). HALF_OUT: write fp16 pre-scaled by ns[row];
// else write fp32 (in-place with xin allowed: block fully stages its rows first).
template<int ACT, int HALF_OUT>
__global__ __launch_bounds__(256) void k_gemm(
        const float* __restrict__ xin, const float* __restrict__ W,
        const float* __restrict__ bias, const float* __restrict__ ns,
        float* __restrict__ fout, __half* __restrict__ hout){
    __shared__ float Wl[64*FEAT];   // 32 KB
    __shared__ float Xl[32*FEAT];   // 16 KB
    int t = threadIdx.x;
    size_t row0 = (size_t)blockIdx.x * 32;
    {
        const float4* src = (const float4*)(xin + row0*FEAT);
        float4* dst = (float4*)Xl;
        for (int i = t; i < 32*FEAT/4; i += 256) dst[i] = src[i];
    }
    int cb = (t & 31) * 4;
    int rb = (t >> 5) * 4;
    float acc[4][4] = {};
    for (int half = 0; half < 2; ++half){
        __syncthreads();
        {
            const float4* src = (const float4*)(W + half*64*FEAT);
            float4* dst = (float4*)Wl;
            for (int i = t; i < 64*FEAT/4; i += 256) dst[i] = src[i];
        }
        __syncthreads();
        for (int k = 0; k < 64; k += 4){
            float a[4][4], w[4][4];
            for (int r = 0; r < 4; ++r){
                float4 v = *(const float4*)&Xl[(rb+r)*FEAT + half*64 + k];
                a[r][0]=v.x; a[r][1]=v.y; a[r][2]=v.z; a[r][3]=v.w;
            }
            for (int kk = 0; kk < 4; ++kk){
                float4 v = *(const float4*)&Wl[(k+kk)*FEAT + cb];
                w[kk][0]=v.x; w[kk][1]=v.y; w[kk][2]=v.z; w[kk][3]=v.w;
            }
            for (int r = 0; r < 4; ++r)
                for (int c = 0; c < 4; ++c)
                    acc[r][c] += a[r][0]*w[0][c] + a[r][1]*w[1][c]
                               + a[r][2]*w[2][c] + a[r][3]*w[3][c];
        }
    }
    float4 bv = *(const float4*)&bias[cb];
    for (int r = 0; r < 4; ++r){
        size_t row = row0 + rb + r;
        float o0 = acc[r][0]+bv.x, o1 = acc[r][1]+bv.y;
        float o2 = acc[r][2]+bv.z, o3 = acc[r][3]+bv.w;
        if (ACT){ o0=selu_f(o0); o1=selu_f(o1); o2=selu_f(o2); o3=selu_f(o3); }
        if (HALF_OUT){
            float w = ns[row];
            union { __half2 h[2]; uint2 u; } pk;
            pk.h[0] = __floats2half2_rn(o0*w, o1*w);
            pk.h[1] = __floats2half2_rn(o2*w, o3*w);
            *(uint2*)&hout[row*FEAT + cb] = pk.u;
        } else {
            float4 o; o.x=o0; o.y=o1; o.z=o2; o.w=o3;
            *(float4*)&fout[row*FEAT + cb] = o;
        }
    }
}

__global__ void k_goff(const int* __restrict__ gid, int* __restrict__ goff){
    int g = blockIdx.x*blockDim.x + threadIdx.x;
    if (g > N_GRAPHS) return;
    if (g == N_GRAPHS){ goff[g] = N_NODES; return; }
    int lo = 0, hi = N_NODES;
    while (lo < hi){
        int mid = (lo + hi) >> 1;
        if (gid[mid] < g) lo = mid + 1; else hi = mid;
    }
    goff[g] = lo;
}

// block per graph, 128 threads = feature columns; segment mean
__global__ void k_readout(const float* __restrict__ x, const int* __restrict__ goff,
                          float* __restrict__ emb){
    int g = blockIdx.x, f = threadIdx.x;
    int beg = goff[g], end = goff[g+1];
    float s = 0.f;
    for (int n = beg; n < end; ++n) s += x[(size_t)n*FEAT + f];
    int c = end - beg; if (c < 1) c = 1;
    emb[g*FEAT + f] = s / (float)c;
}

// block per graph: 136 -> 256 -> 128 -> 1 fused MLP head
__global__ __launch_bounds__(256) void k_mlp(
        const float* __restrict__ emb, const float* __restrict__ fg,
        const float* __restrict__ Wl1, const float* __restrict__ bl1,
        const float* __restrict__ Wl2, const float* __restrict__ bl2,
        const float* __restrict__ Wl3, const float* __restrict__ bl3,
        float* __restrict__ out){
    __shared__ float in136[FEAT+EXTRA];
    __shared__ float y1[256];
    __shared__ float y2[128];
    int g = blockIdx.x, t = threadIdx.x;
    if (t < FEAT)            in136[t] = emb[g*FEAT + t];
    else if (t < FEAT+EXTRA) in136[t] = fg[g*EXTRA + (t-FEAT)];
    __syncthreads();
    {
        float acc = bl1[t];
        for (int i = 0; i < FEAT+EXTRA; ++i) acc += in136[i] * Wl1[i*256 + t];
        y1[t] = selu_f(acc);
    }
    __syncthreads();
    if (t < 128){
        float acc = bl2[t];
        for (int i = 0; i < 256; ++i) acc += y1[i] * Wl2[i*128 + t];
        y2[t] = selu_f(acc);
    }
    __syncthreads();
    if (t == 0){
        float s = bl3[0];
        for (int i = 0; i < 128; ++i) s += y2[i] * Wl3[i];
        out[g] = s;
    }
}

extern "C" void kernel_launch(void* const* d_in, const int* in_sizes, int n_in,
                              void* d_out, int out_size, void* d_ws, size_t ws_size,
                              hipStream_t stream){
    const float* feats_node  = (const float*)d_in[0];
    const float* feats_graph = (const float*)d_in[1];
    const int*   edge_src    = (const int*)d_in[2];
    const int*   edge_dst    = (const int*)d_in[3];
    const int*   graph_ids   = (const int*)d_in[4];
    const float* W1 =(const float*)d_in[5];  const float* b1 =(const float*)d_in[6];
    const float* W2 =(const float*)d_in[7];  const float* b2 =(const float*)d_in[8];
    const float* W3 =(const float*)d_in[9];  const float* b3 =(const float*)d_in[10];
    const float* Wl1=(const float*)d_in[11]; const float* bl1=(const float*)d_in[12];
    const float* Wl2=(const float*)d_in[13]; const float* bl2=(const float*)d_in[14];
    const float* Wl3=(const float*)d_in[15]; const float* bl3=(const float*)d_in[16];
    float* out = (float*)d_out;
    (void)in_sizes; (void)n_in; (void)out_size; (void)ws_size;

    // workspace layout (~86 MB total)
    char* ws = (char*)d_ws;
    size_t off = 0;
    auto alloc = [&](size_t bytes)->void*{
        void* p = ws + off;
        off += (bytes + 255) & ~(size_t)255;
        return p;
    };
    float*  bufA    = (float*) alloc((size_t)N_NODES*FEAT*4);   // fp32 agg / layer out
    __half* xh      = (__half*)alloc((size_t)N_NODES*FEAT*2);   // fp16 pre-scaled gather buf
    float*  ns      = (float*) alloc((size_t)N_NODES*4);
    float*  nd      = (float*) alloc((size_t)N_NODES*4);
    int*    cnt     = (int*)   alloc((size_t)2*N_NODES*4);
    int*    cnt_src = cnt;
    int*    cnt_dst = cnt + N_NODES;
    int*    row_ptr = (int*)   alloc((size_t)(N_NODES+1)*4);
    int*    cursor  = (int*)   alloc((size_t)N_NODES*4);
    int*    col     = (int*)   alloc((size_t)N_EDGES*4);
    int*    bsum    = (int*)   alloc((size_t)SNBLK*4);
    int*    boff    = (int*)   alloc((size_t)SNBLK*4);
    int*    goff    = (int*)   alloc((size_t)(N_GRAPHS+1)*4);
    float*  emb     = (float*) alloc((size_t)N_GRAPHS*FEAT*4);

    // degree counting + norms
    k_zero_i4<<<dim3((2*N_NODES/4 + 255)/256), dim3(256), 0, stream>>>((int4*)cnt, 2*N_NODES/4);
    k_count<<<dim3((N_EDGES+255)/256), dim3(256), 0, stream>>>(edge_src, edge_dst, cnt_src, cnt_dst);
    k_norms<<<dim3((N_NODES+255)/256), dim3(256), 0, stream>>>(cnt_src, cnt_dst, ns, nd);

    // CSR build (by dst)
    k_scan1<<<dim3(SNBLK), dim3(256), 0, stream>>>(cnt_dst, bsum);
    k_scan2<<<dim3(1), dim3(64), 0, stream>>>(bsum, boff, row_ptr);
    k_scan3<<<dim3(SNBLK), dim3(256), 0, stream>>>(cnt_dst, boff, row_ptr, cursor);
    k_scatter<<<dim3((N_EDGES+255)/256), dim3(256), 0, stream>>>(edge_src, edge_dst, cursor, col);

    // fp16 pre-scaled input
    k_prep<<<dim3((N_NODES*64 + 255)/256), dim3(256), 0, stream>>>(
        (const float2*)feats_node, ns, (__half2*)xh);

    // 3 GraphConv layers
    dim3 aggGrid((N_NODES*64 + 255)/256);
    k_aggregate_h<<<aggGrid, dim3(256), 0, stream>>>((const __half2*)xh, row_ptr, col, nd, bufA);
    k_gemm<1,1><<<dim3(N_NODES/32), dim3(256), 0, stream>>>(bufA, W1, b1, ns, (float*)nullptr, xh);
    k_aggregate_h<<<aggGrid, dim3(256), 0, stream>>>((const __half2*)xh, row_ptr, col, nd, bufA);
    k_gemm<1,1><<<dim3(N_NODES/32), dim3(256), 0, stream>>>(bufA, W2, b2, ns, (float*)nullptr, xh);
    k_aggregate_h<<<aggGrid, dim3(256), 0, stream>>>((const __half2*)xh, row_ptr, col, nd, bufA);
    k_gemm<0,0><<<dim3(N_NODES/32), dim3(256), 0, stream>>>(bufA, W3, b3, ns, bufA, (__half*)nullptr);

    // readout + MLP head
    k_goff<<<dim3((N_GRAPHS+1+255)/256), dim3(256), 0, stream>>>(graph_ids, goff);
    k_readout<<<dim3(N_GRAPHS), dim3(FEAT), 0, stream>>>(bufA, goff, emb);
    k_mlp<<<dim3(N_GRAPHS), dim3(256), 0, stream>>>(emb, feats_graph,
        Wl1, bl1, Wl2, bl2, Wl3, bl3, out);
}

// Round 4
// 769.830 us; speedup vs baseline: 1.5500x; 1.3551x over previous
//
#include <hip/hip_runtime.h>
#include <hip/hip_fp16.h>
#include <math.h>

#define N_NODES   100000
#define N_EDGES   1600000
#define N_GRAPHS  512
#define FEAT      128
#define EXTRA     8

#define SCHUNK 512
#define SNBLK ((N_NODES + SCHUNK - 1) / SCHUNK)   // 196

static __device__ __forceinline__ float selu_f(float x){
    const float alpha = 1.6732632423543772f;
    const float scale = 1.0507009873554805f;
    return scale * (x > 0.0f ? x : alpha * expm1f(x));
}

__global__ void k_zero_i4(int4* __restrict__ p, int n4){
    int i = blockIdx.x*blockDim.x + threadIdx.x;
    if (i < n4) p[i] = make_int4(0,0,0,0);
}

__global__ void k_count(const int* __restrict__ esrc, const int* __restrict__ edst,
                        int* __restrict__ cs, int* __restrict__ cd){
    int e = blockIdx.x*blockDim.x + threadIdx.x;
    if (e < N_EDGES){
        atomicAdd(&cs[esrc[e]], 1);
        atomicAdd(&cd[edst[e]], 1);
    }
}

__global__ void k_norms(const int* __restrict__ cs, const int* __restrict__ cd,
                        float* __restrict__ ns, float* __restrict__ nd){
    int i = blockIdx.x*blockDim.x + threadIdx.x;
    if (i < N_NODES){
        ns[i] = rsqrtf((float)(cs[i] > 1 ? cs[i] : 1));
        nd[i] = rsqrtf((float)(cd[i] > 1 ? cd[i] : 1));
    }
}

__global__ void k_scan1(const int* __restrict__ cnt, int* __restrict__ bsum){
    __shared__ int red[256];
    int b = blockIdx.x, t = threadIdx.x;
    int i0 = b*SCHUNK + t;
    int i1 = i0 + 256;
    int v = 0;
    if (i0 < N_NODES) v += cnt[i0];
    if (i1 < N_NODES) v += cnt[i1];
    red[t] = v; __syncthreads();
    for (int s = 128; s > 0; s >>= 1){
        if (t < s) red[t] += red[t+s];
        __syncthreads();
    }
    if (t == 0) bsum[b] = red[0];
}

__global__ void k_scan2(const int* __restrict__ bsum, int* __restrict__ boff,
                        int* __restrict__ row_ptr_tail){
    if (threadIdx.x == 0 && blockIdx.x == 0){
        int run = 0;
        for (int i = 0; i < SNBLK; ++i){ boff[i] = run; run += bsum[i]; }
        if (row_ptr_tail) row_ptr_tail[N_NODES] = N_EDGES;
    }
}

__global__ void k_scan3(const int* __restrict__ cnt, const int* __restrict__ boff,
                        int* __restrict__ row_ptr, int* __restrict__ cursor){
    __shared__ int sc[256];
    int b = blockIdx.x, t = threadIdx.x;
    int base = b*SCHUNK;
    int e0 = base + 2*t, e1 = e0 + 1;
    int a0 = (e0 < N_NODES) ? cnt[e0] : 0;
    int a1 = (e1 < N_NODES) ? cnt[e1] : 0;
    int s = a0 + a1;
    sc[t] = s; __syncthreads();
    for (int d = 1; d < 256; d <<= 1){
        int v = (t >= d) ? sc[t-d] : 0;
        __syncthreads();
        sc[t] += v;
        __syncthreads();
    }
    int excl = sc[t] - s + boff[b];
    if (e0 < N_NODES){ row_ptr[e0] = excl;      cursor[e0] = excl; }
    if (e1 < N_NODES){ row_ptr[e1] = excl + a0; cursor[e1] = excl + a0; }
}

__global__ void k_scatter(const int* __restrict__ esrc, const int* __restrict__ edst,
                          int* __restrict__ cursor, int* __restrict__ col){
    int e = blockIdx.x*blockDim.x + threadIdx.x;
    if (e < N_EDGES){
        int d = edst[e];
        int p = atomicAdd(&cursor[d], 1);
        col[p] = esrc[e];
    }
}

// xh[i] = fp16( x[i] * ns[node] )  -- norm_src pre-folded
__global__ void k_prep(const float2* __restrict__ x2, const float* __restrict__ ns,
                       __half2* __restrict__ xh2){
    int i = blockIdx.x*blockDim.x + threadIdx.x;
    if (i < N_NODES*64){
        int node = i >> 6;
        float w = ns[node];
        float2 v = x2[i];
        xh2[i] = __floats2half2_rn(v.x*w, v.y*w);
    }
}

// one wave per node; wave split 4 subs x 16 lanes; each lane loads 16B (8 fp16
// feats) per edge; 16 edges batched per iteration for deep MLP.
__global__ __launch_bounds__(256) void k_aggregate_h(
        const __half* __restrict__ xh, const int* __restrict__ row_ptr,
        const int* __restrict__ col, const float* __restrict__ nd,
        float* __restrict__ out){
    int gid  = blockIdx.x*blockDim.x + threadIdx.x;
    int node = gid >> 6;
    if (node >= N_NODES) return;
    int lane = threadIdx.x & 63;
    int sub  = lane >> 4;       // 0..3 : edge slot within group of 4
    int fl   = lane & 15;       // 0..15: feature block of 8
    int beg = row_ptr[node], end = row_ptr[node+1];

    float acc[8] = {0,0,0,0,0,0,0,0};
    for (int eb = beg; eb < end; eb += 16){
        int idx[4];
        uint4 r[4];
        #pragma unroll
        for (int j = 0; j < 4; ++j){
            int e = eb + 4*j + sub;
            idx[j] = (e < end) ? col[e] : -1;
        }
        #pragma unroll
        for (int j = 0; j < 4; ++j){
            r[j] = (idx[j] >= 0)
                 ? *(const uint4*)(xh + (size_t)idx[j]*FEAT + fl*8)
                 : make_uint4(0u,0u,0u,0u);
        }
        #pragma unroll
        for (int j = 0; j < 4; ++j){
            const __half2* h = (const __half2*)&r[j];
            #pragma unroll
            for (int q = 0; q < 4; ++q){
                float2 f = __half22float2(h[q]);
                acc[2*q]   += f.x;
                acc[2*q+1] += f.y;
            }
        }
    }
    // reduce across the 4 subs
    #pragma unroll
    for (int q = 0; q < 8; ++q){
        acc[q] += __shfl_xor(acc[q], 16, 64);
        acc[q] += __shfl_xor(acc[q], 32, 64);
    }
    if (lane < 16){
        float wd = nd[node];
        float* op = out + (size_t)node*FEAT + fl*8;
        float4 o0 = make_float4(acc[0]*wd, acc[1]*wd, acc[2]*wd, acc[3]*wd);
        float4 o1 = make_float4(acc[4]*wd, acc[5]*wd, acc[6]*wd, acc[7]*wd);
        *(float4*)op       = o0;
        *(float4*)(op + 4) = o1;
    }
}

// row GEMM: out = act(xin @ W + b). HALF_OUT: write fp16 pre-scaled by ns[row];
// else write fp32 (in-place with xin allowed: block fully stages its rows first).
template<int ACT, int HALF_OUT>
__global__ __launch_bounds__(256) void k_gemm(
        const float* __restrict__ xin, const float* __restrict__ W,
        const float* __restrict__ bias, const float* __restrict__ ns,
        float* __restrict__ fout, __half* __restrict__ hout){
    __shared__ float Wl[64*FEAT];   // 32 KB
    __shared__ float Xl[32*FEAT];   // 16 KB
    int t = threadIdx.x;
    size_t row0 = (size_t)blockIdx.x * 32;
    {
        const float4* src = (const float4*)(xin + row0*FEAT);
        float4* dst = (float4*)Xl;
        for (int i = t; i < 32*FEAT/4; i += 256) dst[i] = src[i];
    }
    int cb = (t & 31) * 4;
    int rb = (t >> 5) * 4;
    float acc[4][4] = {};
    for (int half = 0; half < 2; ++half){
        __syncthreads();
        {
            const float4* src = (const float4*)(W + half*64*FEAT);
            float4* dst = (float4*)Wl;
            for (int i = t; i < 64*FEAT/4; i += 256) dst[i] = src[i];
        }
        __syncthreads();
        for (int k = 0; k < 64; k += 4){
            float a[4][4], w[4][4];
            for (int r = 0; r < 4; ++r){
                float4 v = *(const float4*)&Xl[(rb+r)*FEAT + half*64 + k];
                a[r][0]=v.x; a[r][1]=v.y; a[r][2]=v.z; a[r][3]=v.w;
            }
            for (int kk = 0; kk < 4; ++kk){
                float4 v = *(const float4*)&Wl[(k+kk)*FEAT + cb];
                w[kk][0]=v.x; w[kk][1]=v.y; w[kk][2]=v.z; w[kk][3]=v.w;
            }
            for (int r = 0; r < 4; ++r)
                for (int c = 0; c < 4; ++c)
                    acc[r][c] += a[r][0]*w[0][c] + a[r][1]*w[1][c]
                               + a[r][2]*w[2][c] + a[r][3]*w[3][c];
        }
    }
    float4 bv = *(const float4*)&bias[cb];
    for (int r = 0; r < 4; ++r){
        size_t row = row0 + rb + r;
        float o0 = acc[r][0]+bv.x, o1 = acc[r][1]+bv.y;
        float o2 = acc[r][2]+bv.z, o3 = acc[r][3]+bv.w;
        if (ACT){ o0=selu_f(o0); o1=selu_f(o1); o2=selu_f(o2); o3=selu_f(o3); }
        if (HALF_OUT){
            float w = ns[row];
            union { __half2 h[2]; uint2 u; } pk;
            pk.h[0] = __floats2half2_rn(o0*w, o1*w);
            pk.h[1] = __floats2half2_rn(o2*w, o3*w);
            *(uint2*)&hout[row*FEAT + cb] = pk.u;
        } else {
            float4 o; o.x=o0; o.y=o1; o.z=o2; o.w=o3;
            *(float4*)&fout[row*FEAT + cb] = o;
        }
    }
}

__global__ void k_goff(const int* __restrict__ gid, int* __restrict__ goff){
    int g = blockIdx.x*blockDim.x + threadIdx.x;
    if (g > N_GRAPHS) return;
    if (g == N_GRAPHS){ goff[g] = N_NODES; return; }
    int lo = 0, hi = N_NODES;
    while (lo < hi){
        int mid = (lo + hi) >> 1;
        if (gid[mid] < g) lo = mid + 1; else hi = mid;
    }
    goff[g] = lo;
}

// block per graph, 128 threads = feature columns; segment mean
__global__ void k_readout(const float* __restrict__ x, const int* __restrict__ goff,
                          float* __restrict__ emb){
    int g = blockIdx.x, f = threadIdx.x;
    int beg = goff[g], end = goff[g+1];
    float s = 0.f;
    for (int n = beg; n < end; ++n) s += x[(size_t)n*FEAT + f];
    int c = end - beg; if (c < 1) c = 1;
    emb[g*FEAT + f] = s / (float)c;
}

// block per graph: 136 -> 256 -> 128 -> 1 fused MLP head
__global__ __launch_bounds__(256) void k_mlp(
        const float* __restrict__ emb, const float* __restrict__ fg,
        const float* __restrict__ Wl1, const float* __restrict__ bl1,
        const float* __restrict__ Wl2, const float* __restrict__ bl2,
        const float* __restrict__ Wl3, const float* __restrict__ bl3,
        float* __restrict__ out){
    __shared__ float in136[FEAT+EXTRA];
    __shared__ float y1[256];
    __shared__ float y2[128];
    int g = blockIdx.x, t = threadIdx.x;
    if (t < FEAT)            in136[t] = emb[g*FEAT + t];
    else if (t < FEAT+EXTRA) in136[t] = fg[g*EXTRA + (t-FEAT)];
    __syncthreads();
    {
        float acc = bl1[t];
        for (int i = 0; i < FEAT+EXTRA; ++i) acc += in136[i] * Wl1[i*256 + t];
        y1[t] = selu_f(acc);
    }
    __syncthreads();
    if (t < 128){
        float acc = bl2[t];
        for (int i = 0; i < 256; ++i) acc += y1[i] * Wl2[i*128 + t];
        y2[t] = selu_f(acc);
    }
    __syncthreads();
    if (t == 0){
        float s = bl3[0];
        for (int i = 0; i < 128; ++i) s += y2[i] * Wl3[i];
        out[g] = s;
    }
}

extern "C" void kernel_launch(void* const* d_in, const int* in_sizes, int n_in,
                              void* d_out, int out_size, void* d_ws, size_t ws_size,
                              hipStream_t stream){
    const float* feats_node  = (const float*)d_in[0];
    const float* feats_graph = (const float*)d_in[1];
    const int*   edge_src    = (const int*)d_in[2];
    const int*   edge_dst    = (const int*)d_in[3];
    const int*   graph_ids   = (const int*)d_in[4];
    const float* W1 =(const float*)d_in[5];  const float* b1 =(const float*)d_in[6];
    const float* W2 =(const float*)d_in[7];  const float* b2 =(const float*)d_in[8];
    const float* W3 =(const float*)d_in[9];  const float* b3 =(const float*)d_in[10];
    const float* Wl1=(const float*)d_in[11]; const float* bl1=(const float*)d_in[12];
    const float* Wl2=(const float*)d_in[13]; const float* bl2=(const float*)d_in[14];
    const float* Wl3=(const float*)d_in[15]; const float* bl3=(const float*)d_in[16];
    float* out = (float*)d_out;
    (void)in_sizes; (void)n_in; (void)out_size; (void)ws_size;

    char* ws = (char*)d_ws;
    size_t off = 0;
    auto alloc = [&](size_t bytes)->void*{
        void* p = ws + off;
        off += (bytes + 255) & ~(size_t)255;
        return p;
    };
    float*  bufA    = (float*) alloc((size_t)N_NODES*FEAT*4);   // fp32 agg / layer out
    __half* xh      = (__half*)alloc((size_t)N_NODES*FEAT*2);   // fp16 pre-scaled gather buf
    float*  ns      = (float*) alloc((size_t)N_NODES*4);
    float*  nd      = (float*) alloc((size_t)N_NODES*4);
    int*    cnt     = (int*)   alloc((size_t)2*N_NODES*4);
    int*    cnt_src = cnt;
    int*    cnt_dst = cnt + N_NODES;
    int*    row_ptr = (int*)   alloc((size_t)(N_NODES+1)*4);
    int*    cursor  = (int*)   alloc((size_t)N_NODES*4);
    int*    col     = (int*)   alloc((size_t)N_EDGES*4);
    int*    bsum    = (int*)   alloc((size_t)SNBLK*4);
    int*    boff    = (int*)   alloc((size_t)SNBLK*4);
    int*    goff    = (int*)   alloc((size_t)(N_GRAPHS+1)*4);
    float*  emb     = (float*) alloc((size_t)N_GRAPHS*FEAT*4);

    // degree counting + norms
    k_zero_i4<<<dim3((2*N_NODES/4 + 255)/256), dim3(256), 0, stream>>>((int4*)cnt, 2*N_NODES/4);
    k_count<<<dim3((N_EDGES+255)/256), dim3(256), 0, stream>>>(edge_src, edge_dst, cnt_src, cnt_dst);
    k_norms<<<dim3((N_NODES+255)/256), dim3(256), 0, stream>>>(cnt_src, cnt_dst, ns, nd);

    // CSR build (by dst)
    k_scan1<<<dim3(SNBLK), dim3(256), 0, stream>>>(cnt_dst, bsum);
    k_scan2<<<dim3(1), dim3(64), 0, stream>>>(bsum, boff, row_ptr);
    k_scan3<<<dim3(SNBLK), dim3(256), 0, stream>>>(cnt_dst, boff, row_ptr, cursor);
    k_scatter<<<dim3((N_EDGES+255)/256), dim3(256), 0, stream>>>(edge_src, edge_dst, cursor, col);

    // fp16 pre-scaled input
    k_prep<<<dim3((N_NODES*64 + 255)/256), dim3(256), 0, stream>>>(
        (const float2*)feats_node, ns, (__half2*)xh);

    // 3 GraphConv layers
    dim3 aggGrid((N_NODES*64 + 255)/256);
    k_aggregate_h<<<aggGrid, dim3(256), 0, stream>>>(xh, row_ptr, col, nd, bufA);
    k_gemm<1,1><<<dim3(N_NODES/32), dim3(256), 0, stream>>>(bufA, W1, b1, ns, (float*)nullptr, xh);
    k_aggregate_h<<<aggGrid, dim3(256), 0, stream>>>(xh, row_ptr, col, nd, bufA);
    k_gemm<1,1><<<dim3(N_NODES/32), dim3(256), 0, stream>>>(bufA, W2, b2, ns, (float*)nullptr, xh);
    k_aggregate_h<<<aggGrid, dim3(256), 0, stream>>>(xh, row_ptr, col, nd, bufA);
    k_gemm<0,0><<<dim3(N_NODES/32), dim3(256), 0, stream>>>(bufA, W3, b3, ns, bufA, (__half*)nullptr);

    // readout + MLP head
    k_goff<<<dim3((N_GRAPHS+1+255)/256), dim3(256), 0, stream>>>(graph_ids, goff);
    k_readout<<<dim3(N_GRAPHS), dim3(FEAT), 0, stream>>>(bufA, goff, emb);
    k_mlp<<<dim3(N_GRAPHS), dim3(256), 0, stream>>>(emb, feats_graph,
        Wl1, bl1, Wl2, bl2, Wl3, bl3, out);
}

// Round 5
// 639.645 us; speedup vs baseline: 1.8654x; 1.2035x over previous
//
#include <hip/hip_runtime.h>
#include <hip/hip_fp16.h>
#include <math.h>

#define N_NODES   100000
#define N_EDGES   1600000
#define N_GRAPHS  512
#define FEAT      128
#define EXTRA     8

#define NB    196        // dst buckets of 512 nodes: ceil(100000/512)
#define PA_T  3072       // edges staged per block in pass A
#define PA_K  12         // PA_T / 256

static __device__ __forceinline__ float selu_f(float x){
    const float alpha = 1.6732632423543772f;
    const float scale = 1.0507009873554805f;
    return scale * (x > 0.0f ? x : alpha * expm1f(x));
}

__global__ void k_zero_i4(int4* __restrict__ p, int n4){
    int i = blockIdx.x*blockDim.x + threadIdx.x;
    if (i < n4) p[i] = make_int4(0,0,0,0);
}

__global__ void k_count_src(const int* __restrict__ esrc, int* __restrict__ cs){
    int e = blockIdx.x*blockDim.x + threadIdx.x;
    if (e < N_EDGES) atomicAdd(&cs[esrc[e]], 1);
}

__global__ void k_norms_src(const int* __restrict__ cs, float* __restrict__ ns){
    int i = blockIdx.x*blockDim.x + threadIdx.x;
    if (i < N_NODES) ns[i] = rsqrtf((float)(cs[i] > 1 ? cs[i] : 1));
}

// per-block LDS histogram of dst buckets -> global atomic merge
__global__ __launch_bounds__(256) void k_bhist(const int* __restrict__ edst,
                                               int* __restrict__ bh){
    __shared__ int lh[NB];
    for (int i = threadIdx.x; i < NB; i += 256) lh[i] = 0;
    __syncthreads();
    int stride = gridDim.x * blockDim.x;
    for (int e = blockIdx.x*blockDim.x + threadIdx.x; e < N_EDGES; e += stride)
        atomicAdd(&lh[edst[e] >> 9], 1);
    __syncthreads();
    for (int i = threadIdx.x; i < NB; i += 256)
        if (lh[i]) atomicAdd(&bh[i], lh[i]);
}

__global__ void k_bscan(const int* __restrict__ bh, int* __restrict__ bbase,
                        int* __restrict__ gcursor, int* __restrict__ row_ptr){
    if (threadIdx.x == 0 && blockIdx.x == 0){
        int run = 0;
        for (int i = 0; i < NB; ++i){ bbase[i] = run; gcursor[i] = run; run += bh[i]; }
        bbase[NB] = run;               // == N_EDGES
        row_ptr[N_NODES] = N_EDGES;
    }
}

// pass A: bucket-partition edges into tmp (bucket-grouped), LDS-staged so
// global writes are contiguous runs (kills write amplification)
__global__ __launch_bounds__(256) void k_passA(
        const int* __restrict__ esrc, const int* __restrict__ edst,
        int* __restrict__ gcursor, uint2* __restrict__ tmp){
    __shared__ int   lcount[NB];
    __shared__ int   lscan[256];
    __shared__ int   gbase[NB];
    __shared__ ushort bid[PA_T];
    __shared__ uint2 staged[PA_T];
    __shared__ int   Vtot;
    int t = threadIdx.x;
    int base = blockIdx.x * PA_T;
    for (int i = t; i < NB; i += 256) lcount[i] = 0;
    __syncthreads();
    int bk[PA_K], slot[PA_K]; uint2 pr[PA_K];
    #pragma unroll
    for (int k = 0; k < PA_K; ++k){
        int e = base + k*256 + t;
        if (e < N_EDGES){
            int d = edst[e];
            int s = esrc[e];
            int b = d >> 9;
            bk[k] = b;
            pr[k] = make_uint2((unsigned)d, (unsigned)s);
            slot[k] = atomicAdd(&lcount[b], 1);
        } else bk[k] = -1;
    }
    __syncthreads();
    int v = (t < NB) ? lcount[t] : 0;
    lscan[t] = v;
    __syncthreads();
    for (int d = 1; d < 256; d <<= 1){
        int u = (t >= d) ? lscan[t-d] : 0;
        __syncthreads();
        lscan[t] += u;
        __syncthreads();
    }
    int excl = lscan[t] - v;
    if (t < NB) gbase[t] = atomicAdd(&gcursor[t], v);
    __syncthreads();
    lscan[t] = excl;
    if (t == 255) Vtot = excl + v;
    __syncthreads();
    #pragma unroll
    for (int k = 0; k < PA_K; ++k){
        if (bk[k] >= 0){
            int i = lscan[bk[k]] + slot[k];
            staged[i] = pr[k];
            bid[i] = (ushort)bk[k];
        }
    }
    __syncthreads();
    int total = Vtot;
    for (int i = t; i < total; i += 256){
        int b = bid[i];
        tmp[gbase[b] + (i - lscan[b])] = staged[i];
    }
}

// pass B: one block per bucket. LDS histogram+scan of 512 nodes -> row_ptr,
// nd, then exact-position scatter confined to a ~32KB col window (L2-local).
__global__ __launch_bounds__(256) void k_passB(
        const uint2* __restrict__ tmp, const int* __restrict__ bbase,
        int* __restrict__ row_ptr, int* __restrict__ col, float* __restrict__ nd){
    __shared__ int hc[512];
    __shared__ int hs[512];
    int b = blockIdx.x, t = threadIdx.x;
    int node0 = b << 9;
    int lo = bbase[b], hi = bbase[b+1];
    hc[t] = 0; hc[t+256] = 0;
    __syncthreads();
    for (int p = lo + t; p < hi; p += 256){
        int d = (int)tmp[p].x;
        atomicAdd(&hc[d - node0], 1);
    }
    __syncthreads();
    int a0 = hc[2*t], a1 = hc[2*t+1];
    int s = a0 + a1;
    hs[t] = s;
    __syncthreads();
    for (int d = 1; d < 256; d <<= 1){
        int u = (t >= d) ? hs[t-d] : 0;
        __syncthreads();
        hs[t] += u;
        __syncthreads();
    }
    int excl = hs[t] - s;
    __syncthreads();
    hs[2*t]   = excl;
    hs[2*t+1] = excl + a0;
    int n0 = node0 + 2*t, n1 = n0 + 1;
    if (n0 < N_NODES){
        row_ptr[n0] = lo + excl;
        nd[n0] = rsqrtf((float)(a0 > 1 ? a0 : 1));
    }
    if (n1 < N_NODES){
        row_ptr[n1] = lo + excl + a0;
        nd[n1] = rsqrtf((float)(a1 > 1 ? a1 : 1));
    }
    __syncthreads();
    for (int p = lo + t; p < hi; p += 256){
        uint2 e = tmp[p];
        int slot = atomicAdd(&hs[(int)e.x - node0], 1);
        col[lo + slot] = (int)e.y;
    }
}

// xh[i] = fp16( x[i] * ns[node] )  -- norm_src pre-folded
__global__ void k_prep(const float2* __restrict__ x2, const float* __restrict__ ns,
                       __half2* __restrict__ xh2){
    int i = blockIdx.x*blockDim.x + threadIdx.x;
    if (i < N_NODES*64){
        int node = i >> 6;
        float w = ns[node];
        float2 v = x2[i];
        xh2[i] = __floats2half2_rn(v.x*w, v.y*w);
    }
}

// one wave per node; wave split 4 subs x 16 lanes; each lane loads 16B (8 fp16
// feats) per edge; 16 edges batched per iteration for deep MLP.
__global__ __launch_bounds__(256) void k_aggregate_h(
        const __half* __restrict__ xh, const int* __restrict__ row_ptr,
        const int* __restrict__ col, const float* __restrict__ nd,
        float* __restrict__ out){
    int gid  = blockIdx.x*blockDim.x + threadIdx.x;
    int node = gid >> 6;
    if (node >= N_NODES) return;
    int lane = threadIdx.x & 63;
    int sub  = lane >> 4;
    int fl   = lane & 15;
    int beg = row_ptr[node], end = row_ptr[node+1];

    float acc[8] = {0,0,0,0,0,0,0,0};
    for (int eb = beg; eb < end; eb += 16){
        int idx[4];
        uint4 r[4];
        #pragma unroll
        for (int j = 0; j < 4; ++j){
            int e = eb + 4*j + sub;
            idx[j] = (e < end) ? col[e] : -1;
        }
        #pragma unroll
        for (int j = 0; j < 4; ++j){
            r[j] = (idx[j] >= 0)
                 ? *(const uint4*)(xh + (size_t)idx[j]*FEAT + fl*8)
                 : make_uint4(0u,0u,0u,0u);
        }
        #pragma unroll
        for (int j = 0; j < 4; ++j){
            const __half2* h = (const __half2*)&r[j];
            #pragma unroll
            for (int q = 0; q < 4; ++q){
                float2 f = __half22float2(h[q]);
                acc[2*q]   += f.x;
                acc[2*q+1] += f.y;
            }
        }
    }
    #pragma unroll
    for (int q = 0; q < 8; ++q){
        acc[q] += __shfl_xor(acc[q], 16, 64);
        acc[q] += __shfl_xor(acc[q], 32, 64);
    }
    if (lane < 16){
        float wd = nd[node];
        float* op = out + (size_t)node*FEAT + fl*8;
        *(float4*)op       = make_float4(acc[0]*wd, acc[1]*wd, acc[2]*wd, acc[3]*wd);
        *(float4*)(op + 4) = make_float4(acc[4]*wd, acc[5]*wd, acc[6]*wd, acc[7]*wd);
    }
}

// row GEMM: out = act(xin @ W + b). HALF_OUT: write fp16 pre-scaled by ns[row];
// else write fp32 (in-place with xin allowed: block fully stages its rows first).
template<int ACT, int HALF_OUT>
__global__ __launch_bounds__(256) void k_gemm(
        const float* __restrict__ xin, const float* __restrict__ W,
        const float* __restrict__ bias, const float* __restrict__ ns,
        float* __restrict__ fout, __half* __restrict__ hout){
    __shared__ float Wl[64*FEAT];   // 32 KB
    __shared__ float Xl[32*FEAT];   // 16 KB
    int t = threadIdx.x;
    size_t row0 = (size_t)blockIdx.x * 32;
    {
        const float4* src = (const float4*)(xin + row0*FEAT);
        float4* dst = (float4*)Xl;
        for (int i = t; i < 32*FEAT/4; i += 256) dst[i] = src[i];
    }
    int cb = (t & 31) * 4;
    int rb = (t >> 5) * 4;
    float acc[4][4] = {};
    for (int half = 0; half < 2; ++half){
        __syncthreads();
        {
            const float4* src = (const float4*)(W + half*64*FEAT);
            float4* dst = (float4*)Wl;
            for (int i = t; i < 64*FEAT/4; i += 256) dst[i] = src[i];
        }
        __syncthreads();
        for (int k = 0; k < 64; k += 4){
            float a[4][4], w[4][4];
            for (int r = 0; r < 4; ++r){
                float4 v = *(const float4*)&Xl[(rb+r)*FEAT + half*64 + k];
                a[r][0]=v.x; a[r][1]=v.y; a[r][2]=v.z; a[r][3]=v.w;
            }
            for (int kk = 0; kk < 4; ++kk){
                float4 v = *(const float4*)&Wl[(k+kk)*FEAT + cb];
                w[kk][0]=v.x; w[kk][1]=v.y; w[kk][2]=v.z; w[kk][3]=v.w;
            }
            for (int r = 0; r < 4; ++r)
                for (int c = 0; c < 4; ++c)
                    acc[r][c] += a[r][0]*w[0][c] + a[r][1]*w[1][c]
                               + a[r][2]*w[2][c] + a[r][3]*w[3][c];
        }
    }
    float4 bv = *(const float4*)&bias[cb];
    for (int r = 0; r < 4; ++r){
        size_t row = row0 + rb + r;
        float o0 = acc[r][0]+bv.x, o1 = acc[r][1]+bv.y;
        float o2 = acc[r][2]+bv.z, o3 = acc[r][3]+bv.w;
        if (ACT){ o0=selu_f(o0); o1=selu_f(o1); o2=selu_f(o2); o3=selu_f(o3); }
        if (HALF_OUT){
            float w = ns[row];
            union { __half2 h[2]; uint2 u; } pk;
            pk.h[0] = __floats2half2_rn(o0*w, o1*w);
            pk.h[1] = __floats2half2_rn(o2*w, o3*w);
            *(uint2*)&hout[row*FEAT + cb] = pk.u;
        } else {
            float4 o; o.x=o0; o.y=o1; o.z=o2; o.w=o3;
            *(float4*)&fout[row*FEAT + cb] = o;
        }
    }
}

__global__ void k_goff(const int* __restrict__ gid, int* __restrict__ goff){
    int g = blockIdx.x*blockDim.x + threadIdx.x;
    if (g > N_GRAPHS) return;
    if (g == N_GRAPHS){ goff[g] = N_NODES; return; }
    int lo = 0, hi = N_NODES;
    while (lo < hi){
        int mid = (lo + hi) >> 1;
        if (gid[mid] < g) lo = mid + 1; else hi = mid;
    }
    goff[g] = lo;
}

__global__ void k_readout(const float* __restrict__ x, const int* __restrict__ goff,
                          float* __restrict__ emb){
    int g = blockIdx.x, f = threadIdx.x;
    int beg = goff[g], end = goff[g+1];
    float s = 0.f;
    for (int n = beg; n < end; ++n) s += x[(size_t)n*FEAT + f];
    int c = end - beg; if (c < 1) c = 1;
    emb[g*FEAT + f] = s / (float)c;
}

__global__ __launch_bounds__(256) void k_mlp(
        const float* __restrict__ emb, const float* __restrict__ fg,
        const float* __restrict__ Wl1, const float* __restrict__ bl1,
        const float* __restrict__ Wl2, const float* __restrict__ bl2,
        const float* __restrict__ Wl3, const float* __restrict__ bl3,
        float* __restrict__ out){
    __shared__ float in136[FEAT+EXTRA];
    __shared__ float y1[256];
    __shared__ float y2[128];
    int g = blockIdx.x, t = threadIdx.x;
    if (t < FEAT)            in136[t] = emb[g*FEAT + t];
    else if (t < FEAT+EXTRA) in136[t] = fg[g*EXTRA + (t-FEAT)];
    __syncthreads();
    {
        float acc = bl1[t];
        for (int i = 0; i < FEAT+EXTRA; ++i) acc += in136[i] * Wl1[i*256 + t];
        y1[t] = selu_f(acc);
    }
    __syncthreads();
    if (t < 128){
        float acc = bl2[t];
        for (int i = 0; i < 256; ++i) acc += y1[i] * Wl2[i*128 + t];
        y2[t] = selu_f(acc);
    }
    __syncthreads();
    if (t == 0){
        float s = bl3[0];
        for (int i = 0; i < 128; ++i) s += y2[i] * Wl3[i];
        out[g] = s;
    }
}

extern "C" void kernel_launch(void* const* d_in, const int* in_sizes, int n_in,
                              void* d_out, int out_size, void* d_ws, size_t ws_size,
                              hipStream_t stream){
    const float* feats_node  = (const float*)d_in[0];
    const float* feats_graph = (const float*)d_in[1];
    const int*   edge_src    = (const int*)d_in[2];
    const int*   edge_dst    = (const int*)d_in[3];
    const int*   graph_ids   = (const int*)d_in[4];
    const float* W1 =(const float*)d_in[5];  const float* b1 =(const float*)d_in[6];
    const float* W2 =(const float*)d_in[7];  const float* b2 =(const float*)d_in[8];
    const float* W3 =(const float*)d_in[9];  const float* b3 =(const float*)d_in[10];
    const float* Wl1=(const float*)d_in[11]; const float* bl1=(const float*)d_in[12];
    const float* Wl2=(const float*)d_in[13]; const float* bl2=(const float*)d_in[14];
    const float* Wl3=(const float*)d_in[15]; const float* bl3=(const float*)d_in[16];
    float* out = (float*)d_out;
    (void)in_sizes; (void)n_in; (void)out_size; (void)ws_size;

    char* ws = (char*)d_ws;
    size_t off = 0;
    auto alloc = [&](size_t bytes)->void*{
        void* p = ws + off;
        off += (bytes + 255) & ~(size_t)255;
        return p;
    };
    float*  bufA    = (float*) alloc((size_t)N_NODES*FEAT*4);   // fp32 agg / layer out
    __half* xh      = (__half*)alloc((size_t)N_NODES*FEAT*2);   // fp16 pre-scaled gather buf
    float*  ns      = (float*) alloc((size_t)N_NODES*4);
    float*  nd      = (float*) alloc((size_t)N_NODES*4);
    int*    cntz    = (int*)   alloc((size_t)(N_NODES+256)*4);  // cnt_src + bh (zeroed together)
    int*    cnt_src = cntz;
    int*    bh      = cntz + N_NODES;
    int*    row_ptr = (int*)   alloc((size_t)(N_NODES+1)*4);
    int*    col     = (int*)   alloc((size_t)N_EDGES*4);
    uint2*  tmp     = (uint2*) alloc((size_t)N_EDGES*8);
    int*    bbase   = (int*)   alloc((size_t)(NB+1)*4);
    int*    gcursor = (int*)   alloc((size_t)NB*4);
    int*    goff    = (int*)   alloc((size_t)(N_GRAPHS+1)*4);
    float*  emb     = (float*) alloc((size_t)N_GRAPHS*FEAT*4);

    // zero cnt_src + bh
    k_zero_i4<<<dim3(((N_NODES+256)/4 + 255)/256), dim3(256), 0, stream>>>(
        (int4*)cntz, (N_NODES+256)/4);
    // src degrees (for ns) + dst bucket histogram
    k_count_src<<<dim3((N_EDGES+255)/256), dim3(256), 0, stream>>>(edge_src, cnt_src);
    k_bhist<<<dim3(512), dim3(256), 0, stream>>>(edge_dst, bh);
    k_bscan<<<dim3(1), dim3(64), 0, stream>>>(bh, bbase, gcursor, row_ptr);
    // bucketed CSR build
    k_passA<<<dim3((N_EDGES + PA_T - 1)/PA_T), dim3(256), 0, stream>>>(
        edge_src, edge_dst, gcursor, tmp);
    k_passB<<<dim3(NB), dim3(256), 0, stream>>>(tmp, bbase, row_ptr, col, nd);
    k_norms_src<<<dim3((N_NODES+255)/256), dim3(256), 0, stream>>>(cnt_src, ns);

    // fp16 pre-scaled input
    k_prep<<<dim3((N_NODES*64 + 255)/256), dim3(256), 0, stream>>>(
        (const float2*)feats_node, ns, (__half2*)xh);

    // 3 GraphConv layers
    dim3 aggGrid((N_NODES*64 + 255)/256);
    k_aggregate_h<<<aggGrid, dim3(256), 0, stream>>>(xh, row_ptr, col, nd, bufA);
    k_gemm<1,1><<<dim3(N_NODES/32), dim3(256), 0, stream>>>(bufA, W1, b1, ns, (float*)nullptr, xh);
    k_aggregate_h<<<aggGrid, dim3(256), 0, stream>>>(xh, row_ptr, col, nd, bufA);
    k_gemm<1,1><<<dim3(N_NODES/32), dim3(256), 0, stream>>>(bufA, W2, b2, ns, (float*)nullptr, xh);
    k_aggregate_h<<<aggGrid, dim3(256), 0, stream>>>(xh, row_ptr, col, nd, bufA);
    k_gemm<0,0><<<dim3(N_NODES/32), dim3(256), 0, stream>>>(bufA, W3, b3, ns, bufA, (__half*)nullptr);

    // readout + MLP head
    k_goff<<<dim3((N_GRAPHS+1+255)/256), dim3(256), 0, stream>>>(graph_ids, goff);
    k_readout<<<dim3(N_GRAPHS), dim3(FEAT), 0, stream>>>(bufA, goff, emb);
    k_mlp<<<dim3(N_GRAPHS), dim3(256), 0, stream>>>(emb, feats_graph,
        Wl1, bl1, Wl2, bl2, Wl3, bl3, out);
}

// Round 6
// 489.227 us; speedup vs baseline: 2.4390x; 1.3075x over previous
//
#include <hip/hip_runtime.h>
#include <hip/hip_fp16.h>
#include <math.h>

#define N_NODES   100000
#define N_EDGES   1600000
#define N_GRAPHS  512
#define FEAT      128
#define EXTRA     8

#define NB    196        // dst buckets of 512 nodes
#define PA_T  3072       // edges staged per block in pass A
#define PA_K  12         // PA_T / 256

typedef _Float16 half8_t __attribute__((ext_vector_type(8)));
typedef float    f32x4_t __attribute__((ext_vector_type(4)));

static __device__ __forceinline__ float selu_f(float x){
    const float alpha = 1.6732632423543772f;
    const float scale = 1.0507009873554805f;
    return scale * (x > 0.0f ? x : alpha * expm1f(x));
}

__global__ void k_zero_i4(int4* __restrict__ p, int n4){
    int i = blockIdx.x*blockDim.x + threadIdx.x;
    if (i < n4) p[i] = make_int4(0,0,0,0);
}

__global__ void k_count_src(const int* __restrict__ esrc, int* __restrict__ cs){
    int e = blockIdx.x*blockDim.x + threadIdx.x;
    if (e < N_EDGES) atomicAdd(&cs[esrc[e]], 1);
}

__global__ void k_norms_src(const int* __restrict__ cs, float* __restrict__ ns){
    int i = blockIdx.x*blockDim.x + threadIdx.x;
    if (i < N_NODES) ns[i] = rsqrtf((float)(cs[i] > 1 ? cs[i] : 1));
}

__global__ __launch_bounds__(256) void k_bhist(const int* __restrict__ edst,
                                               int* __restrict__ bh){
    __shared__ int lh[NB];
    for (int i = threadIdx.x; i < NB; i += 256) lh[i] = 0;
    __syncthreads();
    int stride = gridDim.x * blockDim.x;
    for (int e = blockIdx.x*blockDim.x + threadIdx.x; e < N_EDGES; e += stride)
        atomicAdd(&lh[edst[e] >> 9], 1);
    __syncthreads();
    for (int i = threadIdx.x; i < NB; i += 256)
        if (lh[i]) atomicAdd(&bh[i], lh[i]);
}

__global__ void k_bscan(const int* __restrict__ bh, int* __restrict__ bbase,
                        int* __restrict__ gcursor, int* __restrict__ row_ptr){
    if (threadIdx.x == 0 && blockIdx.x == 0){
        int run = 0;
        for (int i = 0; i < NB; ++i){ bbase[i] = run; gcursor[i] = run; run += bh[i]; }
        bbase[NB] = run;
        row_ptr[N_NODES] = N_EDGES;
    }
}

__global__ __launch_bounds__(256) void k_passA(
        const int* __restrict__ esrc, const int* __restrict__ edst,
        int* __restrict__ gcursor, uint2* __restrict__ tmp){
    __shared__ int   lcount[NB];
    __shared__ int   lscan[256];
    __shared__ int   gbase[NB];
    __shared__ ushort bid[PA_T];
    __shared__ uint2 staged[PA_T];
    __shared__ int   Vtot;
    int t = threadIdx.x;
    int base = blockIdx.x * PA_T;
    for (int i = t; i < NB; i += 256) lcount[i] = 0;
    __syncthreads();
    int bk[PA_K], slot[PA_K]; uint2 pr[PA_K];
    #pragma unroll
    for (int k = 0; k < PA_K; ++k){
        int e = base + k*256 + t;
        if (e < N_EDGES){
            int d = edst[e];
            int s = esrc[e];
            int b = d >> 9;
            bk[k] = b;
            pr[k] = make_uint2((unsigned)d, (unsigned)s);
            slot[k] = atomicAdd(&lcount[b], 1);
        } else bk[k] = -1;
    }
    __syncthreads();
    int v = (t < NB) ? lcount[t] : 0;
    lscan[t] = v;
    __syncthreads();
    for (int d = 1; d < 256; d <<= 1){
        int u = (t >= d) ? lscan[t-d] : 0;
        __syncthreads();
        lscan[t] += u;
        __syncthreads();
    }
    int excl = lscan[t] - v;
    if (t < NB) gbase[t] = atomicAdd(&gcursor[t], v);
    __syncthreads();
    lscan[t] = excl;
    if (t == 255) Vtot = excl + v;
    __syncthreads();
    #pragma unroll
    for (int k = 0; k < PA_K; ++k){
        if (bk[k] >= 0){
            int i = lscan[bk[k]] + slot[k];
            staged[i] = pr[k];
            bid[i] = (ushort)bk[k];
        }
    }
    __syncthreads();
    int total = Vtot;
    for (int i = t; i < total; i += 256){
        int b = bid[i];
        tmp[gbase[b] + (i - lscan[b])] = staged[i];
    }
}

__global__ __launch_bounds__(256) void k_passB(
        const uint2* __restrict__ tmp, const int* __restrict__ bbase,
        int* __restrict__ row_ptr, int* __restrict__ col, float* __restrict__ nd){
    __shared__ int hc[512];
    __shared__ int hs[512];
    int b = blockIdx.x, t = threadIdx.x;
    int node0 = b << 9;
    int lo = bbase[b], hi = bbase[b+1];
    hc[t] = 0; hc[t+256] = 0;
    __syncthreads();
    for (int p = lo + t; p < hi; p += 256){
        int d = (int)tmp[p].x;
        atomicAdd(&hc[d - node0], 1);
    }
    __syncthreads();
    int a0 = hc[2*t], a1 = hc[2*t+1];
    int s = a0 + a1;
    hs[t] = s;
    __syncthreads();
    for (int d = 1; d < 256; d <<= 1){
        int u = (t >= d) ? hs[t-d] : 0;
        __syncthreads();
        hs[t] += u;
        __syncthreads();
    }
    int excl = hs[t] - s;
    __syncthreads();
    hs[2*t]   = excl;
    hs[2*t+1] = excl + a0;
    int n0 = node0 + 2*t, n1 = n0 + 1;
    if (n0 < N_NODES){
        row_ptr[n0] = lo + excl;
        nd[n0] = rsqrtf((float)(a0 > 1 ? a0 : 1));
    }
    if (n1 < N_NODES){
        row_ptr[n1] = lo + excl + a0;
        nd[n1] = rsqrtf((float)(a1 > 1 ? a1 : 1));
    }
    __syncthreads();
    for (int p = lo + t; p < hi; p += 256){
        uint2 e = tmp[p];
        int slot = atomicAdd(&hs[(int)e.x - node0], 1);
        col[lo + slot] = (int)e.y;
    }
}

// xh[i] = fp16( x[i] * ns[node] )
__global__ void k_prep(const float2* __restrict__ x2, const float* __restrict__ ns,
                       __half2* __restrict__ xh2){
    int i = blockIdx.x*blockDim.x + threadIdx.x;
    if (i < N_NODES*64){
        int node = i >> 6;
        float w = ns[node];
        float2 v = x2[i];
        xh2[i] = __floats2half2_rn(v.x*w, v.y*w);
    }
}

// swizzle one 128x128 fp32 weight into MFMA-fragment order, fp16:
// Wf[((c*4+kk)*64+lane)*8+j] = W[(kk*32+(lane>>4)*8+j)*128 + c*16+(lane&15)]
__global__ void k_wprep(const float* __restrict__ W, __half* __restrict__ Wf){
    int i = blockIdx.x*256 + threadIdx.x;
    if (i >= 16384) return;
    int j = i & 7, lane = (i>>3) & 63, kk = (i>>9) & 3, c = i>>11;
    int k = kk*32 + ((lane>>4)<<3) + j;
    int cc = (c<<4) + (lane & 15);
    Wf[i] = __float2half(W[k*FEAT + cc]);
}

// one wave per node; wave split 4 subs x 16 lanes; 16B loads; fp16 out (nd folded)
__global__ __launch_bounds__(256) void k_aggregate_h(
        const __half* __restrict__ xh, const int* __restrict__ row_ptr,
        const int* __restrict__ col, const float* __restrict__ nd,
        __half* __restrict__ outh){
    int gid  = blockIdx.x*blockDim.x + threadIdx.x;
    int node = gid >> 6;
    if (node >= N_NODES) return;
    int lane = threadIdx.x & 63;
    int sub  = lane >> 4;
    int fl   = lane & 15;
    int beg = row_ptr[node], end = row_ptr[node+1];

    float acc[8] = {0,0,0,0,0,0,0,0};
    for (int eb = beg; eb < end; eb += 16){
        int idx[4];
        uint4 r[4];
        #pragma unroll
        for (int j = 0; j < 4; ++j){
            int e = eb + 4*j + sub;
            idx[j] = (e < end) ? col[e] : -1;
        }
        #pragma unroll
        for (int j = 0; j < 4; ++j){
            r[j] = (idx[j] >= 0)
                 ? *(const uint4*)(xh + (size_t)idx[j]*FEAT + fl*8)
                 : make_uint4(0u,0u,0u,0u);
        }
        #pragma unroll
        for (int j = 0; j < 4; ++j){
            const __half2* h = (const __half2*)&r[j];
            #pragma unroll
            for (int q = 0; q < 4; ++q){
                float2 f = __half22float2(h[q]);
                acc[2*q]   += f.x;
                acc[2*q+1] += f.y;
            }
        }
    }
    #pragma unroll
    for (int q = 0; q < 8; ++q){
        acc[q] += __shfl_xor(acc[q], 16, 64);
        acc[q] += __shfl_xor(acc[q], 32, 64);
    }
    if (lane < 16){
        float wd = nd[node];
        union { __half2 h[4]; uint4 u; } pk;
        pk.h[0] = __floats2half2_rn(acc[0]*wd, acc[1]*wd);
        pk.h[1] = __floats2half2_rn(acc[2]*wd, acc[3]*wd);
        pk.h[2] = __floats2half2_rn(acc[4]*wd, acc[5]*wd);
        pk.h[3] = __floats2half2_rn(acc[6]*wd, acc[7]*wd);
        *(uint4*)(outh + (size_t)node*FEAT + fl*8) = pk.u;
    }
}

// MFMA GEMM: 64 rows/block (4 waves x 16 rows), full 128 cols per wave.
// A fp16 row-major; Wf fragment-ordered fp16; acc fp32.
// HALF_OUT: hout = fp16(selu(acc+b)*ns); else fout = acc+b (fp32).
template<int ACT, int HALF_OUT>
__global__ __launch_bounds__(256) void k_gemm_mfma(
        const __half* __restrict__ A, const __half* __restrict__ Wf,
        const float* __restrict__ bias, const float* __restrict__ ns,
        float* __restrict__ fout, __half* __restrict__ hout){
    int w = threadIdx.x >> 6, lane = threadIdx.x & 63;
    int r0 = blockIdx.x*64 + w*16;
    int rl = lane & 15, kg = lane >> 4;
    int arow = r0 + rl;

    half8_t a[4];
    if (arow < N_NODES){
        const __half* ap = A + (size_t)arow*FEAT + kg*8;
        #pragma unroll
        for (int kk = 0; kk < 4; ++kk)
            a[kk] = *(const half8_t*)(ap + kk*32);
    } else {
        #pragma unroll
        for (int kk = 0; kk < 4; ++kk) a[kk] = (half8_t)(_Float16)0;
    }

    const half8_t* Bf = (const half8_t*)Wf;
    f32x4_t acc[8];
    #pragma unroll
    for (int c = 0; c < 8; ++c){
        acc[c] = (f32x4_t){0.f,0.f,0.f,0.f};
        #pragma unroll
        for (int kk = 0; kk < 4; ++kk){
            half8_t b = Bf[(c*4 + kk)*64 + lane];
            acc[c] = __builtin_amdgcn_mfma_f32_16x16x32_f16(a[kk], b, acc[c], 0, 0, 0);
        }
    }

    // C/D: col = lane&15, row = (lane>>4)*4 + reg   [m89-verified]
    int orow0 = r0 + kg*4;
    float nsv[4];
    if (HALF_OUT){
        #pragma unroll
        for (int r = 0; r < 4; ++r)
            nsv[r] = (orow0 + r < N_NODES) ? ns[orow0 + r] : 0.f;
    }
    #pragma unroll
    for (int c = 0; c < 8; ++c){
        int ccol = c*16 + rl;
        float bv = bias[ccol];
        #pragma unroll
        for (int r = 0; r < 4; ++r){
            int orow = orow0 + r;
            if (orow < N_NODES){
                float v = acc[c][r] + bv;
                if (ACT) v = selu_f(v);
                if (HALF_OUT) hout[(size_t)orow*FEAT + ccol] = __float2half(v * nsv[r]);
                else          fout[(size_t)orow*FEAT + ccol] = v;
            }
        }
    }
}

__global__ void k_goff(const int* __restrict__ gid, int* __restrict__ goff){
    int g = blockIdx.x*blockDim.x + threadIdx.x;
    if (g > N_GRAPHS) return;
    if (g == N_GRAPHS){ goff[g] = N_NODES; return; }
    int lo = 0, hi = N_NODES;
    while (lo < hi){
        int mid = (lo + hi) >> 1;
        if (gid[mid] < g) lo = mid + 1; else hi = mid;
    }
    goff[g] = lo;
}

__global__ void k_readout(const float* __restrict__ x, const int* __restrict__ goff,
                          float* __restrict__ emb){
    int g = blockIdx.x, f = threadIdx.x;
    int beg = goff[g], end = goff[g+1];
    float s = 0.f;
    for (int n = beg; n < end; ++n) s += x[(size_t)n*FEAT + f];
    int c = end - beg; if (c < 1) c = 1;
    emb[g*FEAT + f] = s / (float)c;
}

__global__ __launch_bounds__(256) void k_mlp(
        const float* __restrict__ emb, const float* __restrict__ fg,
        const float* __restrict__ Wl1, const float* __restrict__ bl1,
        const float* __restrict__ Wl2, const float* __restrict__ bl2,
        const float* __restrict__ Wl3, const float* __restrict__ bl3,
        float* __restrict__ out){
    __shared__ float in136[FEAT+EXTRA];
    __shared__ float y1[256];
    __shared__ float y2[128];
    int g = blockIdx.x, t = threadIdx.x;
    if (t < FEAT)            in136[t] = emb[g*FEAT + t];
    else if (t < FEAT+EXTRA) in136[t] = fg[g*EXTRA + (t-FEAT)];
    __syncthreads();
    {
        float acc = bl1[t];
        for (int i = 0; i < FEAT+EXTRA; ++i) acc += in136[i] * Wl1[i*256 + t];
        y1[t] = selu_f(acc);
    }
    __syncthreads();
    if (t < 128){
        float acc = bl2[t];
        for (int i = 0; i < 256; ++i) acc += y1[i] * Wl2[i*128 + t];
        y2[t] = selu_f(acc);
    }
    __syncthreads();
    if (t == 0){
        float s = bl3[0];
        for (int i = 0; i < 128; ++i) s += y2[i] * Wl3[i];
        out[g] = s;
    }
}

extern "C" void kernel_launch(void* const* d_in, const int* in_sizes, int n_in,
                              void* d_out, int out_size, void* d_ws, size_t ws_size,
                              hipStream_t stream){
    const float* feats_node  = (const float*)d_in[0];
    const float* feats_graph = (const float*)d_in[1];
    const int*   edge_src    = (const int*)d_in[2];
    const int*   edge_dst    = (const int*)d_in[3];
    const int*   graph_ids   = (const int*)d_in[4];
    const float* W1 =(const float*)d_in[5];  const float* b1 =(const float*)d_in[6];
    const float* W2 =(const float*)d_in[7];  const float* b2 =(const float*)d_in[8];
    const float* W3 =(const float*)d_in[9];  const float* b3 =(const float*)d_in[10];
    const float* Wl1=(const float*)d_in[11]; const float* bl1=(const float*)d_in[12];
    const float* Wl2=(const float*)d_in[13]; const float* bl2=(const float*)d_in[14];
    const float* Wl3=(const float*)d_in[15]; const float* bl3=(const float*)d_in[16];
    float* out = (float*)d_out;
    (void)in_sizes; (void)n_in; (void)out_size; (void)ws_size;

    char* ws = (char*)d_ws;
    size_t off = 0;
    auto alloc = [&](size_t bytes)->void*{
        void* p = ws + off;
        off += (bytes + 255) & ~(size_t)255;
        return p;
    };
    float*  bufA    = (float*) alloc((size_t)N_NODES*FEAT*4);   // fp32 final layer out
    __half* xh      = (__half*)alloc((size_t)N_NODES*FEAT*2);   // fp16 gather buf (ns folded)
    __half* ah      = (__half*)alloc((size_t)N_NODES*FEAT*2);   // fp16 agg out (nd folded)
    float*  ns      = (float*) alloc((size_t)N_NODES*4);
    float*  nd      = (float*) alloc((size_t)N_NODES*4);
    int*    cntz    = (int*)   alloc((size_t)(N_NODES+256)*4);
    int*    cnt_src = cntz;
    int*    bh      = cntz + N_NODES;
    int*    row_ptr = (int*)   alloc((size_t)(N_NODES+1)*4);
    int*    col     = (int*)   alloc((size_t)N_EDGES*4);
    uint2*  tmp     = (uint2*) alloc((size_t)N_EDGES*8);
    int*    bbase   = (int*)   alloc((size_t)(NB+1)*4);
    int*    gcursor = (int*)   alloc((size_t)NB*4);
    __half* Wf1     = (__half*)alloc((size_t)16384*2);
    __half* Wf2     = (__half*)alloc((size_t)16384*2);
    __half* Wf3     = (__half*)alloc((size_t)16384*2);
    int*    goff    = (int*)   alloc((size_t)(N_GRAPHS+1)*4);
    float*  emb     = (float*) alloc((size_t)N_GRAPHS*FEAT*4);

    k_zero_i4<<<dim3(((N_NODES+256)/4 + 255)/256), dim3(256), 0, stream>>>(
        (int4*)cntz, (N_NODES+256)/4);
    k_count_src<<<dim3((N_EDGES+255)/256), dim3(256), 0, stream>>>(edge_src, cnt_src);
    k_bhist<<<dim3(512), dim3(256), 0, stream>>>(edge_dst, bh);
    k_bscan<<<dim3(1), dim3(64), 0, stream>>>(bh, bbase, gcursor, row_ptr);
    k_passA<<<dim3((N_EDGES + PA_T - 1)/PA_T), dim3(256), 0, stream>>>(
        edge_src, edge_dst, gcursor, tmp);
    k_passB<<<dim3(NB), dim3(256), 0, stream>>>(tmp, bbase, row_ptr, col, nd);
    k_norms_src<<<dim3((N_NODES+255)/256), dim3(256), 0, stream>>>(cnt_src, ns);

    // weight fragment swizzle (fp16)
    k_wprep<<<dim3(64), dim3(256), 0, stream>>>(W1, Wf1);
    k_wprep<<<dim3(64), dim3(256), 0, stream>>>(W2, Wf2);
    k_wprep<<<dim3(64), dim3(256), 0, stream>>>(W3, Wf3);

    // fp16 pre-scaled input
    k_prep<<<dim3((N_NODES*64 + 255)/256), dim3(256), 0, stream>>>(
        (const float2*)feats_node, ns, (__half2*)xh);

    // 3 GraphConv layers: aggregate (fp16 out) -> MFMA GEMM
    dim3 aggGrid((N_NODES*64 + 255)/256);
    dim3 gemmGrid((N_NODES + 63)/64);
    k_aggregate_h<<<aggGrid, dim3(256), 0, stream>>>(xh, row_ptr, col, nd, ah);
    k_gemm_mfma<1,1><<<gemmGrid, dim3(256), 0, stream>>>(ah, Wf1, b1, ns, (float*)nullptr, xh);
    k_aggregate_h<<<aggGrid, dim3(256), 0, stream>>>(xh, row_ptr, col, nd, ah);
    k_gemm_mfma<1,1><<<gemmGrid, dim3(256), 0, stream>>>(ah, Wf2, b2, ns, (float*)nullptr, xh);
    k_aggregate_h<<<aggGrid, dim3(256), 0, stream>>>(xh, row_ptr, col, nd, ah);
    k_gemm_mfma<0,0><<<gemmGrid, dim3(256), 0, stream>>>(ah, Wf3, b3, ns, bufA, (__half*)nullptr);

    // readout + MLP head
    k_goff<<<dim3((N_GRAPHS+1+255)/256), dim3(256), 0, stream>>>(graph_ids, goff);
    k_readout<<<dim3(N_GRAPHS), dim3(FEAT), 0, stream>>>(bufA, goff, emb);
    k_mlp<<<dim3(N_GRAPHS), dim3(256), 0, stream>>>(emb, feats_graph,
        Wl1, bl1, Wl2, bl2, Wl3, bl3, out);
}

// Round 7
// 462.091 us; speedup vs baseline: 2.5822x; 1.0587x over previous
//
#include <hip/hip_runtime.h>
#include <hip/hip_fp16.h>
#include <math.h>

#define N_NODES   100000
#define N_EDGES   1600000
#define N_GRAPHS  512
#define FEAT      128
#define EXTRA     8

#define NB    196        // buckets of 512 nodes
#define PA_T  3072       // edges staged per block in pass A
#define PA_K  12         // PA_T / 256

typedef _Float16 half8_t __attribute__((ext_vector_type(8)));
typedef float    f32x4_t __attribute__((ext_vector_type(4)));

static __device__ __forceinline__ float selu_f(float x){
    const float alpha = 1.6732632423543772f;
    const float scale = 1.0507009873554805f;
    return scale * (x > 0.0f ? x : alpha * expm1f(x));
}

__global__ void k_zero_i4(int4* __restrict__ p, int n4){
    int i = blockIdx.x*blockDim.x + threadIdx.x;
    if (i < n4) p[i] = make_int4(0,0,0,0);
}

// bucket histograms for BOTH src and dst in one pass (LDS-privatized)
__global__ __launch_bounds__(256) void k_bhist2(
        const int* __restrict__ esrc, const int* __restrict__ edst,
        int* __restrict__ bh_src, int* __restrict__ bh_dst){
    __shared__ int lhs[NB];
    __shared__ int lhd[NB];
    for (int i = threadIdx.x; i < NB; i += 256){ lhs[i] = 0; lhd[i] = 0; }
    __syncthreads();
    int stride = gridDim.x * blockDim.x;
    for (int e = blockIdx.x*blockDim.x + threadIdx.x; e < N_EDGES; e += stride){
        atomicAdd(&lhs[esrc[e] >> 9], 1);
        atomicAdd(&lhd[edst[e] >> 9], 1);
    }
    __syncthreads();
    for (int i = threadIdx.x; i < NB; i += 256){
        if (lhs[i]) atomicAdd(&bh_src[i], lhs[i]);
        if (lhd[i]) atomicAdd(&bh_dst[i], lhd[i]);
    }
}

__global__ void k_bscan2(const int* __restrict__ bh_dst, int* __restrict__ bbase,
                         int* __restrict__ gcursor, int* __restrict__ row_ptr,
                         const int* __restrict__ bh_src, int* __restrict__ sbase,
                         int* __restrict__ scursor){
    if (threadIdx.x == 0 && blockIdx.x == 0){
        int run = 0;
        for (int i = 0; i < NB; ++i){ bbase[i] = run; gcursor[i] = run; run += bh_dst[i]; }
        bbase[NB] = run;
        row_ptr[N_NODES] = N_EDGES;
        run = 0;
        for (int i = 0; i < NB; ++i){ sbase[i] = run; scursor[i] = run; run += bh_src[i]; }
        sbase[NB] = run;
    }
}

// pass A (dst): bucket-partition (dst,src) pairs into tmp, LDS-staged
__global__ __launch_bounds__(256) void k_passA(
        const int* __restrict__ esrc, const int* __restrict__ edst,
        int* __restrict__ gcursor, uint2* __restrict__ tmp){
    __shared__ int   lcount[NB];
    __shared__ int   lscan[256];
    __shared__ int   gbase[NB];
    __shared__ ushort bid[PA_T];
    __shared__ uint2 staged[PA_T];
    __shared__ int   Vtot;
    int t = threadIdx.x;
    int base = blockIdx.x * PA_T;
    for (int i = t; i < NB; i += 256) lcount[i] = 0;
    __syncthreads();
    int bk[PA_K], slot[PA_K]; uint2 pr[PA_K];
    #pragma unroll
    for (int k = 0; k < PA_K; ++k){
        int e = base + k*256 + t;
        if (e < N_EDGES){
            int d = edst[e];
            int s = esrc[e];
            int b = d >> 9;
            bk[k] = b;
            pr[k] = make_uint2((unsigned)d, (unsigned)s);
            slot[k] = atomicAdd(&lcount[b], 1);
        } else bk[k] = -1;
    }
    __syncthreads();
    int v = (t < NB) ? lcount[t] : 0;
    lscan[t] = v;
    __syncthreads();
    for (int d = 1; d < 256; d <<= 1){
        int u = (t >= d) ? lscan[t-d] : 0;
        __syncthreads();
        lscan[t] += u;
        __syncthreads();
    }
    int excl = lscan[t] - v;
    if (t < NB) gbase[t] = atomicAdd(&gcursor[t], v);
    __syncthreads();
    lscan[t] = excl;
    if (t == 255) Vtot = excl + v;
    __syncthreads();
    #pragma unroll
    for (int k = 0; k < PA_K; ++k){
        if (bk[k] >= 0){
            int i = lscan[bk[k]] + slot[k];
            staged[i] = pr[k];
            bid[i] = (ushort)bk[k];
        }
    }
    __syncthreads();
    int total = Vtot;
    for (int i = t; i < total; i += 256){
        int b = bid[i];
        tmp[gbase[b] + (i - lscan[b])] = staged[i];
    }
}

// pass A (src): bucket-partition src low-bits (ushort) into tmp2, LDS-staged
__global__ __launch_bounds__(256) void k_passA_src(
        const int* __restrict__ esrc, int* __restrict__ scursor,
        ushort* __restrict__ tmp2){
    __shared__ int    lcount[NB];
    __shared__ int    lscan[256];
    __shared__ int    gbase[NB];
    __shared__ ushort bid[PA_T];
    __shared__ ushort staged[PA_T];
    __shared__ int    Vtot;
    int t = threadIdx.x;
    int base = blockIdx.x * PA_T;
    for (int i = t; i < NB; i += 256) lcount[i] = 0;
    __syncthreads();
    int bk[PA_K], slot[PA_K]; ushort pv[PA_K];
    #pragma unroll
    for (int k = 0; k < PA_K; ++k){
        int e = base + k*256 + t;
        if (e < N_EDGES){
            int s = esrc[e];
            int b = s >> 9;
            bk[k] = b;
            pv[k] = (ushort)(s & 511);
            slot[k] = atomicAdd(&lcount[b], 1);
        } else bk[k] = -1;
    }
    __syncthreads();
    int v = (t < NB) ? lcount[t] : 0;
    lscan[t] = v;
    __syncthreads();
    for (int d = 1; d < 256; d <<= 1){
        int u = (t >= d) ? lscan[t-d] : 0;
        __syncthreads();
        lscan[t] += u;
        __syncthreads();
    }
    int excl = lscan[t] - v;
    if (t < NB) gbase[t] = atomicAdd(&scursor[t], v);
    __syncthreads();
    lscan[t] = excl;
    if (t == 255) Vtot = excl + v;
    __syncthreads();
    #pragma unroll
    for (int k = 0; k < PA_K; ++k){
        if (bk[k] >= 0){
            int i = lscan[bk[k]] + slot[k];
            staged[i] = pv[k];
            bid[i] = (ushort)bk[k];
        }
    }
    __syncthreads();
    int total = Vtot;
    for (int i = t; i < total; i += 256){
        int b = bid[i];
        tmp2[gbase[b] + (i - lscan[b])] = staged[i];
    }
}

// per src-bucket LDS histogram -> ns
__global__ __launch_bounds__(256) void k_srchist(
        const ushort* __restrict__ tmp2, const int* __restrict__ sbase,
        float* __restrict__ ns){
    __shared__ int hc[512];
    int b = blockIdx.x, t = threadIdx.x;
    int node0 = b << 9;
    int lo = sbase[b], hi = sbase[b+1];
    hc[t] = 0; hc[t+256] = 0;
    __syncthreads();
    for (int p = lo + t; p < hi; p += 256)
        atomicAdd(&hc[tmp2[p]], 1);
    __syncthreads();
    int n0 = node0 + t, n1 = n0 + 256;
    if (n0 < N_NODES){ int c = hc[t];     ns[n0] = rsqrtf((float)(c > 1 ? c : 1)); }
    if (n1 < N_NODES){ int c = hc[t+256]; ns[n1] = rsqrtf((float)(c > 1 ? c : 1)); }
}

// pass B: one block per dst bucket -> row_ptr, nd, col (L2-local scatter)
__global__ __launch_bounds__(256) void k_passB(
        const uint2* __restrict__ tmp, const int* __restrict__ bbase,
        int* __restrict__ row_ptr, int* __restrict__ col, float* __restrict__ nd){
    __shared__ int hc[512];
    __shared__ int hs[512];
    int b = blockIdx.x, t = threadIdx.x;
    int node0 = b << 9;
    int lo = bbase[b], hi = bbase[b+1];
    hc[t] = 0; hc[t+256] = 0;
    __syncthreads();
    for (int p = lo + t; p < hi; p += 256){
        int d = (int)tmp[p].x;
        atomicAdd(&hc[d - node0], 1);
    }
    __syncthreads();
    int a0 = hc[2*t], a1 = hc[2*t+1];
    int s = a0 + a1;
    hs[t] = s;
    __syncthreads();
    for (int d = 1; d < 256; d <<= 1){
        int u = (t >= d) ? hs[t-d] : 0;
        __syncthreads();
        hs[t] += u;
        __syncthreads();
    }
    int excl = hs[t] - s;
    __syncthreads();
    hs[2*t]   = excl;
    hs[2*t+1] = excl + a0;
    int n0 = node0 + 2*t, n1 = n0 + 1;
    if (n0 < N_NODES){
        row_ptr[n0] = lo + excl;
        nd[n0] = rsqrtf((float)(a0 > 1 ? a0 : 1));
    }
    if (n1 < N_NODES){
        row_ptr[n1] = lo + excl + a0;
        nd[n1] = rsqrtf((float)(a1 > 1 ? a1 : 1));
    }
    __syncthreads();
    for (int p = lo + t; p < hi; p += 256){
        uint2 e = tmp[p];
        int slot = atomicAdd(&hs[(int)e.x - node0], 1);
        col[lo + slot] = (int)e.y;
    }
}

// xh[i] = fp16( x[i] * ns[node] )
__global__ void k_prep(const float2* __restrict__ x2, const float* __restrict__ ns,
                       __half2* __restrict__ xh2){
    int i = blockIdx.x*blockDim.x + threadIdx.x;
    if (i < N_NODES*64){
        int node = i >> 6;
        float w = ns[node];
        float2 v = x2[i];
        xh2[i] = __floats2half2_rn(v.x*w, v.y*w);
    }
}

// swizzle one 128x128 fp32 weight into MFMA-fragment order, fp16
__global__ void k_wprep(const float* __restrict__ W, __half* __restrict__ Wf){
    int i = blockIdx.x*256 + threadIdx.x;
    if (i >= 16384) return;
    int j = i & 7, lane = (i>>3) & 63, kk = (i>>9) & 3, c = i>>11;
    int k = kk*32 + ((lane>>4)<<3) + j;
    int cc = (c<<4) + (lane & 15);
    Wf[i] = __float2half(W[k*FEAT + cc]);
}

// one wave per node; wave split 4 subs x 16 lanes; 16B loads; fp16 out (nd folded)
__global__ __launch_bounds__(256) void k_aggregate_h(
        const __half* __restrict__ xh, const int* __restrict__ row_ptr,
        const int* __restrict__ col, const float* __restrict__ nd,
        __half* __restrict__ outh){
    int gid  = blockIdx.x*blockDim.x + threadIdx.x;
    int node = gid >> 6;
    if (node >= N_NODES) return;
    int lane = threadIdx.x & 63;
    int sub  = lane >> 4;
    int fl   = lane & 15;
    int beg = row_ptr[node], end = row_ptr[node+1];

    float acc[8] = {0,0,0,0,0,0,0,0};
    for (int eb = beg; eb < end; eb += 16){
        int idx[4];
        uint4 r[4];
        #pragma unroll
        for (int j = 0; j < 4; ++j){
            int e = eb + 4*j + sub;
            idx[j] = (e < end) ? col[e] : -1;
        }
        #pragma unroll
        for (int j = 0; j < 4; ++j){
            r[j] = (idx[j] >= 0)
                 ? *(const uint4*)(xh + (size_t)idx[j]*FEAT + fl*8)
                 : make_uint4(0u,0u,0u,0u);
        }
        #pragma unroll
        for (int j = 0; j < 4; ++j){
            const __half2* h = (const __half2*)&r[j];
            #pragma unroll
            for (int q = 0; q < 4; ++q){
                float2 f = __half22float2(h[q]);
                acc[2*q]   += f.x;
                acc[2*q+1] += f.y;
            }
        }
    }
    #pragma unroll
    for (int q = 0; q < 8; ++q){
        acc[q] += __shfl_xor(acc[q], 16, 64);
        acc[q] += __shfl_xor(acc[q], 32, 64);
    }
    if (lane < 16){
        float wd = nd[node];
        union { __half2 h[4]; uint4 u; } pk;
        pk.h[0] = __floats2half2_rn(acc[0]*wd, acc[1]*wd);
        pk.h[1] = __floats2half2_rn(acc[2]*wd, acc[3]*wd);
        pk.h[2] = __floats2half2_rn(acc[4]*wd, acc[5]*wd);
        pk.h[3] = __floats2half2_rn(acc[6]*wd, acc[7]*wd);
        *(uint4*)(outh + (size_t)node*FEAT + fl*8) = pk.u;
    }
}

// MFMA GEMM: 64 rows/block (4 waves x 16 rows), full 128 cols per wave.
template<int ACT, int HALF_OUT>
__global__ __launch_bounds__(256) void k_gemm_mfma(
        const __half* __restrict__ A, const __half* __restrict__ Wf,
        const float* __restrict__ bias, const float* __restrict__ ns,
        float* __restrict__ fout, __half* __restrict__ hout){
    int w = threadIdx.x >> 6, lane = threadIdx.x & 63;
    int r0 = blockIdx.x*64 + w*16;
    int rl = lane & 15, kg = lane >> 4;
    int arow = r0 + rl;

    half8_t a[4];
    if (arow < N_NODES){
        const __half* ap = A + (size_t)arow*FEAT + kg*8;
        #pragma unroll
        for (int kk = 0; kk < 4; ++kk)
            a[kk] = *(const half8_t*)(ap + kk*32);
    } else {
        #pragma unroll
        for (int kk = 0; kk < 4; ++kk) a[kk] = (half8_t)(_Float16)0;
    }

    const half8_t* Bf = (const half8_t*)Wf;
    f32x4_t acc[8];
    #pragma unroll
    for (int c = 0; c < 8; ++c){
        acc[c] = (f32x4_t){0.f,0.f,0.f,0.f};
        #pragma unroll
        for (int kk = 0; kk < 4; ++kk){
            half8_t b = Bf[(c*4 + kk)*64 + lane];
            acc[c] = __builtin_amdgcn_mfma_f32_16x16x32_f16(a[kk], b, acc[c], 0, 0, 0);
        }
    }

    int orow0 = r0 + kg*4;
    float nsv[4];
    if (HALF_OUT){
        #pragma unroll
        for (int r = 0; r < 4; ++r)
            nsv[r] = (orow0 + r < N_NODES) ? ns[orow0 + r] : 0.f;
    }
    #pragma unroll
    for (int c = 0; c < 8; ++c){
        int ccol = c*16 + rl;
        float bv = bias[ccol];
        #pragma unroll
        for (int r = 0; r < 4; ++r){
            int orow = orow0 + r;
            if (orow < N_NODES){
                float v = acc[c][r] + bv;
                if (ACT) v = selu_f(v);
                if (HALF_OUT) hout[(size_t)orow*FEAT + ccol] = __float2half(v * nsv[r]);
                else          fout[(size_t)orow*FEAT + ccol] = v;
            }
        }
    }
}

__global__ void k_goff(const int* __restrict__ gid, int* __restrict__ goff){
    int g = blockIdx.x*blockDim.x + threadIdx.x;
    if (g > N_GRAPHS) return;
    if (g == N_GRAPHS){ goff[g] = N_NODES; return; }
    int lo = 0, hi = N_NODES;
    while (lo < hi){
        int mid = (lo + hi) >> 1;
        if (gid[mid] < g) lo = mid + 1; else hi = mid;
    }
    goff[g] = lo;
}

__global__ void k_readout(const float* __restrict__ x, const int* __restrict__ goff,
                          float* __restrict__ emb){
    int g = blockIdx.x, f = threadIdx.x;
    int beg = goff[g], end = goff[g+1];
    float s = 0.f;
    for (int n = beg; n < end; ++n) s += x[(size_t)n*FEAT + f];
    int c = end - beg; if (c < 1) c = 1;
    emb[g*FEAT + f] = s / (float)c;
}

__global__ __launch_bounds__(256) void k_mlp(
        const float* __restrict__ emb, const float* __restrict__ fg,
        const float* __restrict__ Wl1, const float* __restrict__ bl1,
        const float* __restrict__ Wl2, const float* __restrict__ bl2,
        const float* __restrict__ Wl3, const float* __restrict__ bl3,
        float* __restrict__ out){
    __shared__ float in136[FEAT+EXTRA];
    __shared__ float y1[256];
    __shared__ float y2[128];
    int g = blockIdx.x, t = threadIdx.x;
    if (t < FEAT)            in136[t] = emb[g*FEAT + t];
    else if (t < FEAT+EXTRA) in136[t] = fg[g*EXTRA + (t-FEAT)];
    __syncthreads();
    {
        float acc = bl1[t];
        for (int i = 0; i < FEAT+EXTRA; ++i) acc += in136[i] * Wl1[i*256 + t];
        y1[t] = selu_f(acc);
    }
    __syncthreads();
    if (t < 128){
        float acc = bl2[t];
        for (int i = 0; i < 256; ++i) acc += y1[i] * Wl2[i*128 + t];
        y2[t] = selu_f(acc);
    }
    __syncthreads();
    if (t == 0){
        float s = bl3[0];
        for (int i = 0; i < 128; ++i) s += y2[i] * Wl3[i];
        out[g] = s;
    }
}

extern "C" void kernel_launch(void* const* d_in, const int* in_sizes, int n_in,
                              void* d_out, int out_size, void* d_ws, size_t ws_size,
                              hipStream_t stream){
    const float* feats_node  = (const float*)d_in[0];
    const float* feats_graph = (const float*)d_in[1];
    const int*   edge_src    = (const int*)d_in[2];
    const int*   edge_dst    = (const int*)d_in[3];
    const int*   graph_ids   = (const int*)d_in[4];
    const float* W1 =(const float*)d_in[5];  const float* b1 =(const float*)d_in[6];
    const float* W2 =(const float*)d_in[7];  const float* b2 =(const float*)d_in[8];
    const float* W3 =(const float*)d_in[9];  const float* b3 =(const float*)d_in[10];
    const float* Wl1=(const float*)d_in[11]; const float* bl1=(const float*)d_in[12];
    const float* Wl2=(const float*)d_in[13]; const float* bl2=(const float*)d_in[14];
    const float* Wl3=(const float*)d_in[15]; const float* bl3=(const float*)d_in[16];
    float* out = (float*)d_out;
    (void)in_sizes; (void)n_in; (void)out_size; (void)ws_size;

    char* ws = (char*)d_ws;
    size_t off = 0;
    auto alloc = [&](size_t bytes)->void*{
        void* p = ws + off;
        off += (bytes + 255) & ~(size_t)255;
        return p;
    };
    float*  bufA    = (float*) alloc((size_t)N_NODES*FEAT*4);   // fp32 final layer out
    __half* xh      = (__half*)alloc((size_t)N_NODES*FEAT*2);   // fp16 gather buf (ns folded)
    __half* ah      = (__half*)alloc((size_t)N_NODES*FEAT*2);   // fp16 agg out (nd folded)
    float*  ns      = (float*) alloc((size_t)N_NODES*4);
    float*  nd      = (float*) alloc((size_t)N_NODES*4);
    int*    bhz     = (int*)   alloc((size_t)2*NB*4);           // bh_src + bh_dst (zeroed)
    int*    bh_src  = bhz;
    int*    bh_dst  = bhz + NB;
    int*    row_ptr = (int*)   alloc((size_t)(N_NODES+1)*4);
    int*    col     = (int*)   alloc((size_t)N_EDGES*4);
    uint2*  tmp     = (uint2*) alloc((size_t)N_EDGES*8);
    ushort* tmp2    = (ushort*)alloc((size_t)N_EDGES*2);
    int*    bbase   = (int*)   alloc((size_t)(NB+1)*4);
    int*    gcursor = (int*)   alloc((size_t)NB*4);
    int*    sbase   = (int*)   alloc((size_t)(NB+1)*4);
    int*    scursor = (int*)   alloc((size_t)NB*4);
    __half* Wf1     = (__half*)alloc((size_t)16384*2);
    __half* Wf2     = (__half*)alloc((size_t)16384*2);
    __half* Wf3     = (__half*)alloc((size_t)16384*2);
    int*    goff    = (int*)   alloc((size_t)(N_GRAPHS+1)*4);
    float*  emb     = (float*) alloc((size_t)N_GRAPHS*FEAT*4);

    // zero bucket histograms (2*196 ints)
    k_zero_i4<<<dim3(1), dim3(128), 0, stream>>>((int4*)bhz, 2*NB/4);
    // bucket histograms (src+dst), scans
    k_bhist2<<<dim3(512), dim3(256), 0, stream>>>(edge_src, edge_dst, bh_src, bh_dst);
    k_bscan2<<<dim3(1), dim3(64), 0, stream>>>(bh_dst, bbase, gcursor, row_ptr,
                                               bh_src, sbase, scursor);
    // bucketed CSR build (dst) + src-degree build
    k_passA<<<dim3((N_EDGES + PA_T - 1)/PA_T), dim3(256), 0, stream>>>(
        edge_src, edge_dst, gcursor, tmp);
    k_passA_src<<<dim3((N_EDGES + PA_T - 1)/PA_T), dim3(256), 0, stream>>>(
        edge_src, scursor, tmp2);
    k_passB<<<dim3(NB), dim3(256), 0, stream>>>(tmp, bbase, row_ptr, col, nd);
    k_srchist<<<dim3(NB), dim3(256), 0, stream>>>(tmp2, sbase, ns);

    // weight fragment swizzle (fp16)
    k_wprep<<<dim3(64), dim3(256), 0, stream>>>(W1, Wf1);
    k_wprep<<<dim3(64), dim3(256), 0, stream>>>(W2, Wf2);
    k_wprep<<<dim3(64), dim3(256), 0, stream>>>(W3, Wf3);

    // fp16 pre-scaled input
    k_prep<<<dim3((N_NODES*64 + 255)/256), dim3(256), 0, stream>>>(
        (const float2*)feats_node, ns, (__half2*)xh);

    // 3 GraphConv layers: aggregate (fp16 out) -> MFMA GEMM
    dim3 aggGrid((N_NODES*64 + 255)/256);
    dim3 gemmGrid((N_NODES + 63)/64);
    k_aggregate_h<<<aggGrid, dim3(256), 0, stream>>>(xh, row_ptr, col, nd, ah);
    k_gemm_mfma<1,1><<<gemmGrid, dim3(256), 0, stream>>>(ah, Wf1, b1, ns, (float*)nullptr, xh);
    k_aggregate_h<<<aggGrid, dim3(256), 0, stream>>>(xh, row_ptr, col, nd, ah);
    k_gemm_mfma<1,1><<<gemmGrid, dim3(256), 0, stream>>>(ah, Wf2, b2, ns, (float*)nullptr, xh);
    k_aggregate_h<<<aggGrid, dim3(256), 0, stream>>>(xh, row_ptr, col, nd, ah);
    k_gemm_mfma<0,0><<<gemmGrid, dim3(256), 0, stream>>>(ah, Wf3, b3, ns, bufA, (__half*)nullptr);

    // readout + MLP head
    k_goff<<<dim3((N_GRAPHS+1+255)/256), dim3(256), 0, stream>>>(graph_ids, goff);
    k_readout<<<dim3(N_GRAPHS), dim3(FEAT), 0, stream>>>(bufA, goff, emb);
    k_mlp<<<dim3(N_GRAPHS), dim3(256), 0, stream>>>(emb, feats_graph,
        Wl1, bl1, Wl2, bl2, Wl3, bl3, out);
}

// Round 8
// 379.406 us; speedup vs baseline: 3.1449x; 1.2179x over previous
//
#include <hip/hip_runtime.h>
#include <hip/hip_fp16.h>
#include <math.h>

#define N_NODES   100000
#define N_EDGES   1600000
#define N_GRAPHS  512
#define FEAT      128
#define EXTRA     8

#define NB    196        // buckets of 512 nodes
#define PA_T  3072       // edges staged per block in pass A
#define PA_K  12         // PA_T / 256

typedef _Float16 half8_t __attribute__((ext_vector_type(8)));
typedef float    f32x4_t __attribute__((ext_vector_type(4)));

static __device__ __forceinline__ float selu_f(float x){
    const float alpha = 1.6732632423543772f;
    const float scale = 1.0507009873554805f;
    return scale * (x > 0.0f ? x : alpha * expm1f(x));
}

__global__ void k_zero_i4(int4* __restrict__ p, int n4){
    int i = blockIdx.x*blockDim.x + threadIdx.x;
    if (i < n4) p[i] = make_int4(0,0,0,0);
}

// bucket histograms for BOTH src and dst in one pass (LDS-privatized)
__global__ __launch_bounds__(256) void k_bhist2(
        const int* __restrict__ esrc, const int* __restrict__ edst,
        int* __restrict__ bh_src, int* __restrict__ bh_dst){
    __shared__ int lhs[NB];
    __shared__ int lhd[NB];
    for (int i = threadIdx.x; i < NB; i += 256){ lhs[i] = 0; lhd[i] = 0; }
    __syncthreads();
    int stride = gridDim.x * blockDim.x;
    for (int e = blockIdx.x*blockDim.x + threadIdx.x; e < N_EDGES; e += stride){
        atomicAdd(&lhs[esrc[e] >> 9], 1);
        atomicAdd(&lhd[edst[e] >> 9], 1);
    }
    __syncthreads();
    for (int i = threadIdx.x; i < NB; i += 256){
        if (lhs[i]) atomicAdd(&bh_src[i], lhs[i]);
        if (lhd[i]) atomicAdd(&bh_dst[i], lhd[i]);
    }
}

__global__ void k_bscan2(const int* __restrict__ bh_dst, int* __restrict__ bbase,
                         int* __restrict__ gcursor, int* __restrict__ row_ptr,
                         const int* __restrict__ bh_src, int* __restrict__ sbase,
                         int* __restrict__ scursor){
    if (threadIdx.x == 0 && blockIdx.x == 0){
        int run = 0;
        for (int i = 0; i < NB; ++i){ bbase[i] = run; gcursor[i] = run; run += bh_dst[i]; }
        bbase[NB] = run;
        row_ptr[N_NODES] = N_EDGES;
        run = 0;
        for (int i = 0; i < NB; ++i){ sbase[i] = run; scursor[i] = run; run += bh_src[i]; }
        sbase[NB] = run;
    }
}

// pass A (dst): bucket-partition (dst,src) pairs into tmp, LDS-staged
__global__ __launch_bounds__(256) void k_passA(
        const int* __restrict__ esrc, const int* __restrict__ edst,
        int* __restrict__ gcursor, uint2* __restrict__ tmp){
    __shared__ int   lcount[NB];
    __shared__ int   lscan[256];
    __shared__ int   gbase[NB];
    __shared__ ushort bid[PA_T];
    __shared__ uint2 staged[PA_T];
    __shared__ int   Vtot;
    int t = threadIdx.x;
    int base = blockIdx.x * PA_T;
    for (int i = t; i < NB; i += 256) lcount[i] = 0;
    __syncthreads();
    int bk[PA_K], slot[PA_K]; uint2 pr[PA_K];
    #pragma unroll
    for (int k = 0; k < PA_K; ++k){
        int e = base + k*256 + t;
        if (e < N_EDGES){
            int d = edst[e];
            int s = esrc[e];
            int b = d >> 9;
            bk[k] = b;
            pr[k] = make_uint2((unsigned)d, (unsigned)s);
            slot[k] = atomicAdd(&lcount[b], 1);
        } else bk[k] = -1;
    }
    __syncthreads();
    int v = (t < NB) ? lcount[t] : 0;
    lscan[t] = v;
    __syncthreads();
    for (int d = 1; d < 256; d <<= 1){
        int u = (t >= d) ? lscan[t-d] : 0;
        __syncthreads();
        lscan[t] += u;
        __syncthreads();
    }
    int excl = lscan[t] - v;
    if (t < NB) gbase[t] = atomicAdd(&gcursor[t], v);
    __syncthreads();
    lscan[t] = excl;
    if (t == 255) Vtot = excl + v;
    __syncthreads();
    #pragma unroll
    for (int k = 0; k < PA_K; ++k){
        if (bk[k] >= 0){
            int i = lscan[bk[k]] + slot[k];
            staged[i] = pr[k];
            bid[i] = (ushort)bk[k];
        }
    }
    __syncthreads();
    int total = Vtot;
    for (int i = t; i < total; i += 256){
        int b = bid[i];
        tmp[gbase[b] + (i - lscan[b])] = staged[i];
    }
}

// pass A (src): bucket-partition src low-bits (ushort) into tmp2, LDS-staged
__global__ __launch_bounds__(256) void k_passA_src(
        const int* __restrict__ esrc, int* __restrict__ scursor,
        ushort* __restrict__ tmp2){
    __shared__ int    lcount[NB];
    __shared__ int    lscan[256];
    __shared__ int    gbase[NB];
    __shared__ ushort bid[PA_T];
    __shared__ ushort staged[PA_T];
    __shared__ int    Vtot;
    int t = threadIdx.x;
    int base = blockIdx.x * PA_T;
    for (int i = t; i < NB; i += 256) lcount[i] = 0;
    __syncthreads();
    int bk[PA_K], slot[PA_K]; ushort pv[PA_K];
    #pragma unroll
    for (int k = 0; k < PA_K; ++k){
        int e = base + k*256 + t;
        if (e < N_EDGES){
            int s = esrc[e];
            int b = s >> 9;
            bk[k] = b;
            pv[k] = (ushort)(s & 511);
            slot[k] = atomicAdd(&lcount[b], 1);
        } else bk[k] = -1;
    }
    __syncthreads();
    int v = (t < NB) ? lcount[t] : 0;
    lscan[t] = v;
    __syncthreads();
    for (int d = 1; d < 256; d <<= 1){
        int u = (t >= d) ? lscan[t-d] : 0;
        __syncthreads();
        lscan[t] += u;
        __syncthreads();
    }
    int excl = lscan[t] - v;
    if (t < NB) gbase[t] = atomicAdd(&scursor[t], v);
    __syncthreads();
    lscan[t] = excl;
    if (t == 255) Vtot = excl + v;
    __syncthreads();
    #pragma unroll
    for (int k = 0; k < PA_K; ++k){
        if (bk[k] >= 0){
            int i = lscan[bk[k]] + slot[k];
            staged[i] = pv[k];
            bid[i] = (ushort)bk[k];
        }
    }
    __syncthreads();
    int total = Vtot;
    for (int i = t; i < total; i += 256){
        int b = bid[i];
        tmp2[gbase[b] + (i - lscan[b])] = staged[i];
    }
}

// per src-bucket LDS histogram -> ns
__global__ __launch_bounds__(256) void k_srchist(
        const ushort* __restrict__ tmp2, const int* __restrict__ sbase,
        float* __restrict__ ns){
    __shared__ int hc[512];
    int b = blockIdx.x, t = threadIdx.x;
    int node0 = b << 9;
    int lo = sbase[b], hi = sbase[b+1];
    hc[t] = 0; hc[t+256] = 0;
    __syncthreads();
    for (int p = lo + t; p < hi; p += 256)
        atomicAdd(&hc[tmp2[p]], 1);
    __syncthreads();
    int n0 = node0 + t, n1 = n0 + 256;
    if (n0 < N_NODES){ int c = hc[t];     ns[n0] = rsqrtf((float)(c > 1 ? c : 1)); }
    if (n1 < N_NODES){ int c = hc[t+256]; ns[n1] = rsqrtf((float)(c > 1 ? c : 1)); }
}

// pass B: one block per dst bucket -> row_ptr, nd, col (L2-local scatter)
__global__ __launch_bounds__(256) void k_passB(
        const uint2* __restrict__ tmp, const int* __restrict__ bbase,
        int* __restrict__ row_ptr, int* __restrict__ col, float* __restrict__ nd){
    __shared__ int hc[512];
    __shared__ int hs[512];
    int b = blockIdx.x, t = threadIdx.x;
    int node0 = b << 9;
    int lo = bbase[b], hi = bbase[b+1];
    hc[t] = 0; hc[t+256] = 0;
    __syncthreads();
    for (int p = lo + t; p < hi; p += 256){
        int d = (int)tmp[p].x;
        atomicAdd(&hc[d - node0], 1);
    }
    __syncthreads();
    int a0 = hc[2*t], a1 = hc[2*t+1];
    int s = a0 + a1;
    hs[t] = s;
    __syncthreads();
    for (int d = 1; d < 256; d <<= 1){
        int u = (t >= d) ? hs[t-d] : 0;
        __syncthreads();
        hs[t] += u;
        __syncthreads();
    }
    int excl = hs[t] - s;
    __syncthreads();
    hs[2*t]   = excl;
    hs[2*t+1] = excl + a0;
    int n0 = node0 + 2*t, n1 = n0 + 1;
    if (n0 < N_NODES){
        row_ptr[n0] = lo + excl;
        nd[n0] = rsqrtf((float)(a0 > 1 ? a0 : 1));
    }
    if (n1 < N_NODES){
        row_ptr[n1] = lo + excl + a0;
        nd[n1] = rsqrtf((float)(a1 > 1 ? a1 : 1));
    }
    __syncthreads();
    for (int p = lo + t; p < hi; p += 256){
        uint2 e = tmp[p];
        int slot = atomicAdd(&hs[(int)e.x - node0], 1);
        col[lo + slot] = (int)e.y;
    }
}

// xh[i] = fp16( x[i] * ns[node] )
__global__ void k_prep(const float2* __restrict__ x2, const float* __restrict__ ns,
                       __half2* __restrict__ xh2){
    int i = blockIdx.x*blockDim.x + threadIdx.x;
    if (i < N_NODES*64){
        int node = i >> 6;
        float w = ns[node];
        float2 v = x2[i];
        xh2[i] = __floats2half2_rn(v.x*w, v.y*w);
    }
}

// swizzle one 128x128 fp32 weight into MFMA-fragment order, fp16
__global__ void k_wprep(const float* __restrict__ W, __half* __restrict__ Wf){
    int i = blockIdx.x*256 + threadIdx.x;
    if (i >= 16384) return;
    int j = i & 7, lane = (i>>3) & 63, kk = (i>>9) & 3, c = i>>11;
    int k = kk*32 + ((lane>>4)<<3) + j;
    int cc = (c<<4) + (lane & 15);
    Wf[i] = __float2half(W[k*FEAT + cc]);
}

// one wave per node; wave split 4 subs x 16 lanes; 16B loads; fp16 out (nd folded)
__global__ __launch_bounds__(256) void k_aggregate_h(
        const __half* __restrict__ xh, const int* __restrict__ row_ptr,
        const int* __restrict__ col, const float* __restrict__ nd,
        __half* __restrict__ outh){
    int gid  = blockIdx.x*blockDim.x + threadIdx.x;
    int node = gid >> 6;
    if (node >= N_NODES) return;
    int lane = threadIdx.x & 63;
    int sub  = lane >> 4;
    int fl   = lane & 15;
    int beg = row_ptr[node], end = row_ptr[node+1];

    float acc[8] = {0,0,0,0,0,0,0,0};
    for (int eb = beg; eb < end; eb += 16){
        int idx[4];
        uint4 r[4];
        #pragma unroll
        for (int j = 0; j < 4; ++j){
            int e = eb + 4*j + sub;
            idx[j] = (e < end) ? col[e] : -1;
        }
        #pragma unroll
        for (int j = 0; j < 4; ++j){
            r[j] = (idx[j] >= 0)
                 ? *(const uint4*)(xh + (size_t)idx[j]*FEAT + fl*8)
                 : make_uint4(0u,0u,0u,0u);
        }
        #pragma unroll
        for (int j = 0; j < 4; ++j){
            const __half2* h = (const __half2*)&r[j];
            #pragma unroll
            for (int q = 0; q < 4; ++q){
                float2 f = __half22float2(h[q]);
                acc[2*q]   += f.x;
                acc[2*q+1] += f.y;
            }
        }
    }
    #pragma unroll
    for (int q = 0; q < 8; ++q){
        acc[q] += __shfl_xor(acc[q], 16, 64);
        acc[q] += __shfl_xor(acc[q], 32, 64);
    }
    if (lane < 16){
        float wd = nd[node];
        union { __half2 h[4]; uint4 u; } pk;
        pk.h[0] = __floats2half2_rn(acc[0]*wd, acc[1]*wd);
        pk.h[1] = __floats2half2_rn(acc[2]*wd, acc[3]*wd);
        pk.h[2] = __floats2half2_rn(acc[4]*wd, acc[5]*wd);
        pk.h[3] = __floats2half2_rn(acc[6]*wd, acc[7]*wd);
        *(uint4*)(outh + (size_t)node*FEAT + fl*8) = pk.u;
    }
}

// MFMA GEMM: 64 rows/block (4 waves x 16 rows), full 128 cols per wave.
template<int ACT, int HALF_OUT>
__global__ __launch_bounds__(256) void k_gemm_mfma(
        const __half* __restrict__ A, const __half* __restrict__ Wf,
        const float* __restrict__ bias, const float* __restrict__ ns,
        float* __restrict__ fout, __half* __restrict__ hout){
    int w = threadIdx.x >> 6, lane = threadIdx.x & 63;
    int r0 = blockIdx.x*64 + w*16;
    int rl = lane & 15, kg = lane >> 4;
    int arow = r0 + rl;

    half8_t a[4];
    if (arow < N_NODES){
        const __half* ap = A + (size_t)arow*FEAT + kg*8;
        #pragma unroll
        for (int kk = 0; kk < 4; ++kk)
            a[kk] = *(const half8_t*)(ap + kk*32);
    } else {
        #pragma unroll
        for (int kk = 0; kk < 4; ++kk) a[kk] = (half8_t)(_Float16)0;
    }

    const half8_t* Bf = (const half8_t*)Wf;
    f32x4_t acc[8];
    #pragma unroll
    for (int c = 0; c < 8; ++c){
        acc[c] = (f32x4_t){0.f,0.f,0.f,0.f};
        #pragma unroll
        for (int kk = 0; kk < 4; ++kk){
            half8_t b = Bf[(c*4 + kk)*64 + lane];
            acc[c] = __builtin_amdgcn_mfma_f32_16x16x32_f16(a[kk], b, acc[c], 0, 0, 0);
        }
    }

    int orow0 = r0 + kg*4;
    float nsv[4];
    if (HALF_OUT){
        #pragma unroll
        for (int r = 0; r < 4; ++r)
            nsv[r] = (orow0 + r < N_NODES) ? ns[orow0 + r] : 0.f;
    }
    #pragma unroll
    for (int c = 0; c < 8; ++c){
        int ccol = c*16 + rl;
        float bv = bias[ccol];
        #pragma unroll
        for (int r = 0; r < 4; ++r){
            int orow = orow0 + r;
            if (orow < N_NODES){
                float v = acc[c][r] + bv;
                if (ACT) v = selu_f(v);
                if (HALF_OUT) hout[(size_t)orow*FEAT + ccol] = __float2half(v * nsv[r]);
                else          fout[(size_t)orow*FEAT + ccol] = v;
            }
        }
    }
}

__global__ void k_goff(const int* __restrict__ gid, int* __restrict__ goff){
    int g = blockIdx.x*blockDim.x + threadIdx.x;
    if (g > N_GRAPHS) return;
    if (g == N_GRAPHS){ goff[g] = N_NODES; return; }
    int lo = 0, hi = N_NODES;
    while (lo < hi){
        int mid = (lo + hi) >> 1;
        if (gid[mid] < g) lo = mid + 1; else hi = mid;
    }
    goff[g] = lo;
}

// readout on fp16 aggregate: 4 chunk-blocks per graph, 16 rows x 16 uint4 lanes
__global__ __launch_bounds__(256) void k_readout_h(
        const __half* __restrict__ ah, const int* __restrict__ goff,
        float* __restrict__ emb_part){
    __shared__ float red[16][FEAT];
    int g = blockIdx.x >> 2, c = blockIdx.x & 3;
    int t = threadIdx.x;
    int fl = t & 15, rs = t >> 4;
    int beg = goff[g], end = goff[g+1];
    int cnt = end - beg;
    int chunk = (cnt + 3) >> 2;
    int lo = beg + c*chunk;
    int hi = lo + chunk; if (hi > end) hi = end;
    float acc[8] = {0,0,0,0,0,0,0,0};
    for (int r = lo + rs; r < hi; r += 16){
        uint4 v = *(const uint4*)(ah + (size_t)r*FEAT + fl*8);
        const __half2* h = (const __half2*)&v;
        #pragma unroll
        for (int q = 0; q < 4; ++q){
            float2 f = __half22float2(h[q]);
            acc[2*q]   += f.x;
            acc[2*q+1] += f.y;
        }
    }
    #pragma unroll
    for (int q = 0; q < 8; ++q) red[rs][fl*8+q] = acc[q];
    __syncthreads();
    if (t < FEAT){
        float s = 0.f;
        #pragma unroll
        for (int i = 0; i < 16; ++i) s += red[i][t];
        emb_part[((size_t)g*4 + c)*FEAT + t] = s;
    }
}

// block per graph: mean(parts) -> @W3+b3 -> concat fg -> 136->256->128->1 MLP
__global__ __launch_bounds__(256) void k_mlp(
        const float* __restrict__ emb_part, const int* __restrict__ goff,
        const float* __restrict__ fg,
        const float* __restrict__ W3, const float* __restrict__ b3,
        const float* __restrict__ Wl1, const float* __restrict__ bl1,
        const float* __restrict__ Wl2, const float* __restrict__ bl2,
        const float* __restrict__ Wl3, const float* __restrict__ bl3,
        float* __restrict__ out){
    __shared__ float e[FEAT];
    __shared__ float in136[FEAT+EXTRA];
    __shared__ float y1[256];
    __shared__ float y2[128];
    int g = blockIdx.x, t = threadIdx.x;
    int cnt = goff[g+1] - goff[g]; if (cnt < 1) cnt = 1;
    float inv = 1.f / (float)cnt;
    if (t < FEAT){
        const float* p = emb_part + (size_t)g*4*FEAT;
        e[t] = (p[t] + p[FEAT+t] + p[2*FEAT+t] + p[3*FEAT+t]) * inv;
    }
    else if (t < FEAT+EXTRA + 128) { /* nothing */ }
    __syncthreads();
    if (t < FEAT){
        float acc = b3[t];
        for (int i = 0; i < FEAT; ++i) acc += e[i] * W3[i*FEAT + t];
        in136[t] = acc;
    } else if (t < FEAT+EXTRA){
        in136[t] = fg[g*EXTRA + (t-FEAT)];
    }
    __syncthreads();
    {
        float acc = bl1[t];
        for (int i = 0; i < FEAT+EXTRA; ++i) acc += in136[i] * Wl1[i*256 + t];
        y1[t] = selu_f(acc);
    }
    __syncthreads();
    if (t < 128){
        float acc = bl2[t];
        for (int i = 0; i < 256; ++i) acc += y1[i] * Wl2[i*128 + t];
        y2[t] = selu_f(acc);
    }
    __syncthreads();
    if (t == 0){
        float s = bl3[0];
        for (int i = 0; i < 128; ++i) s += y2[i] * Wl3[i];
        out[g] = s;
    }
}

extern "C" void kernel_launch(void* const* d_in, const int* in_sizes, int n_in,
                              void* d_out, int out_size, void* d_ws, size_t ws_size,
                              hipStream_t stream){
    const float* feats_node  = (const float*)d_in[0];
    const float* feats_graph = (const float*)d_in[1];
    const int*   edge_src    = (const int*)d_in[2];
    const int*   edge_dst    = (const int*)d_in[3];
    const int*   graph_ids   = (const int*)d_in[4];
    const float* W1 =(const float*)d_in[5];  const float* b1 =(const float*)d_in[6];
    const float* W2 =(const float*)d_in[7];  const float* b2 =(const float*)d_in[8];
    const float* W3 =(const float*)d_in[9];  const float* b3 =(const float*)d_in[10];
    const float* Wl1=(const float*)d_in[11]; const float* bl1=(const float*)d_in[12];
    const float* Wl2=(const float*)d_in[13]; const float* bl2=(const float*)d_in[14];
    const float* Wl3=(const float*)d_in[15]; const float* bl3=(const float*)d_in[16];
    float* out = (float*)d_out;
    (void)in_sizes; (void)n_in; (void)out_size; (void)ws_size;

    char* ws = (char*)d_ws;
    size_t off = 0;
    auto alloc = [&](size_t bytes)->void*{
        void* p = ws + off;
        off += (bytes + 255) & ~(size_t)255;
        return p;
    };
    __half* xh      = (__half*)alloc((size_t)N_NODES*FEAT*2);   // fp16 gather buf (ns folded)
    __half* ah      = (__half*)alloc((size_t)N_NODES*FEAT*2);   // fp16 agg out (nd folded)
    float*  ns      = (float*) alloc((size_t)N_NODES*4);
    float*  nd      = (float*) alloc((size_t)N_NODES*4);
    int*    bhz     = (int*)   alloc((size_t)2*NB*4);
    int*    bh_src  = bhz;
    int*    bh_dst  = bhz + NB;
    int*    row_ptr = (int*)   alloc((size_t)(N_NODES+1)*4);
    int*    col     = (int*)   alloc((size_t)N_EDGES*4);
    uint2*  tmp     = (uint2*) alloc((size_t)N_EDGES*8);
    ushort* tmp2    = (ushort*)alloc((size_t)N_EDGES*2);
    int*    bbase   = (int*)   alloc((size_t)(NB+1)*4);
    int*    gcursor = (int*)   alloc((size_t)NB*4);
    int*    sbase   = (int*)   alloc((size_t)(NB+1)*4);
    int*    scursor = (int*)   alloc((size_t)NB*4);
    __half* Wf1     = (__half*)alloc((size_t)16384*2);
    __half* Wf2     = (__half*)alloc((size_t)16384*2);
    int*    goff    = (int*)   alloc((size_t)(N_GRAPHS+1)*4);
    float*  emb_part= (float*) alloc((size_t)N_GRAPHS*4*FEAT*4);

    // zero bucket histograms
    k_zero_i4<<<dim3(1), dim3(128), 0, stream>>>((int4*)bhz, 2*NB/4);
    // bucket histograms (src+dst), scans
    k_bhist2<<<dim3(512), dim3(256), 0, stream>>>(edge_src, edge_dst, bh_src, bh_dst);
    k_bscan2<<<dim3(1), dim3(64), 0, stream>>>(bh_dst, bbase, gcursor, row_ptr,
                                               bh_src, sbase, scursor);
    // bucketed CSR build (dst) + src-degree build
    k_passA<<<dim3((N_EDGES + PA_T - 1)/PA_T), dim3(256), 0, stream>>>(
        edge_src, edge_dst, gcursor, tmp);
    k_passA_src<<<dim3((N_EDGES + PA_T - 1)/PA_T), dim3(256), 0, stream>>>(
        edge_src, scursor, tmp2);
    k_passB<<<dim3(NB), dim3(256), 0, stream>>>(tmp, bbase, row_ptr, col, nd);
    k_srchist<<<dim3(NB), dim3(256), 0, stream>>>(tmp2, sbase, ns);

    // weight fragment swizzle (fp16) — layers 1,2 only (layer 3 folded into MLP)
    k_wprep<<<dim3(64), dim3(256), 0, stream>>>(W1, Wf1);
    k_wprep<<<dim3(64), dim3(256), 0, stream>>>(W2, Wf2);

    // fp16 pre-scaled input
    k_prep<<<dim3((N_NODES*64 + 255)/256), dim3(256), 0, stream>>>(
        (const float2*)feats_node, ns, (__half2*)xh);

    // graph offsets (needed by readout)
    k_goff<<<dim3((N_GRAPHS+1+255)/256), dim3(256), 0, stream>>>(graph_ids, goff);

    // 3 GraphConv layers; third GEMM is linear -> folded after readout
    dim3 aggGrid((N_NODES*64 + 255)/256);
    dim3 gemmGrid((N_NODES + 63)/64);
    k_aggregate_h<<<aggGrid, dim3(256), 0, stream>>>(xh, row_ptr, col, nd, ah);
    k_gemm_mfma<1,1><<<gemmGrid, dim3(256), 0, stream>>>(ah, Wf1, b1, ns, (float*)nullptr, xh);
    k_aggregate_h<<<aggGrid, dim3(256), 0, stream>>>(xh, row_ptr, col, nd, ah);
    k_gemm_mfma<1,1><<<gemmGrid, dim3(256), 0, stream>>>(ah, Wf2, b2, ns, (float*)nullptr, xh);
    k_aggregate_h<<<aggGrid, dim3(256), 0, stream>>>(xh, row_ptr, col, nd, ah);

    // readout on fp16 aggregate + fused (mean @ W3 + b3) inside MLP
    k_readout_h<<<dim3(N_GRAPHS*4), dim3(256), 0, stream>>>(ah, goff, emb_part);
    k_mlp<<<dim3(N_GRAPHS), dim3(256), 0, stream>>>(emb_part, goff, feats_graph,
        W3, b3, Wl1, bl1, Wl2, bl2, Wl3, bl3, out);
}